// Round 7
// baseline (394.921 us; speedup 1.0000x reference)
//
#include <hip/hip_runtime.h>

#define NN      100000
#define MHE     200000
#define EE      2000000
#define H1      400000      // hedge keys (2 types)
#define K2N     200000      // node keys (2 types)
#define NB1     782         // side-1 coarse buckets (512 hedge-keys each)
#define NB2     391         // side-2 coarse buckets (512 node-keys each)
#define NCB2    320         // partition blocks
#define CHK2    6250        // edges per partition block (320*6250 = EE exactly)
#define FCN     375360      // (NB1+NB2)*NCB2 flat counters
#define SCB2    367         // ceil(FCN/1024)
#define CAP1    3584        // max items per side-1 bucket (mean 2560)
#define CAP2    6144        // max items per side-2 bucket (mean 5120)

typedef unsigned short u16;
typedef unsigned int   u32;
typedef unsigned long long ull;
typedef __attribute__((ext_vector_type(8))) short  s16x8;
typedef __attribute__((ext_vector_type(4))) float  f32x4;
typedef __attribute__((ext_vector_type(4))) unsigned int u32x4;

__device__ __forceinline__ float bf2f(u16 u) { return __uint_as_float(((u32)u) << 16); }
__device__ __forceinline__ u16 f2bf(float f) {
    u32 u = __float_as_uint(f);
    return (u16)((u + 0x7fffu + ((u >> 16) & 1u)) >> 16);
}
__device__ __forceinline__ float ldv(const void* p, long i, int isf32) {
    return isf32 ? ((const float*)p)[i] : bf2f(((const u16*)p)[i]);
}
__device__ __forceinline__ u16 ldb(const void* p, long i, int isf32) {
    return isf32 ? f2bf(((const float*)p)[i]) : ((const u16*)p)[i];
}
__device__ __forceinline__ void stv(void* p, long i, float v, int isf32) {
    if (isf32) ((float*)p)[i] = v;
    else       ((u16*)p)[i] = f2bf(v);
}

union FragU { s16x8 v; ull q[2]; u16 u[8]; };

__device__ __forceinline__ s16x8 ld8bf(const void* p, long off, int isf32) {
    FragU f;
    if (isf32) {
        const float* fp = (const float*)p + off;
        f32x4 a = *(const f32x4*)fp;
        f32x4 b = *(const f32x4*)(fp + 4);
        f.u[0]=f2bf(a[0]); f.u[1]=f2bf(a[1]); f.u[2]=f2bf(a[2]); f.u[3]=f2bf(a[3]);
        f.u[4]=f2bf(b[0]); f.u[5]=f2bf(b[1]); f.u[6]=f2bf(b[2]); f.u[7]=f2bf(b[3]);
    } else {
        u32x4 w = *(const u32x4*)((const u16*)p + off);
        f.q[0] = ((ull)w[1] << 32) | w[0];
        f.q[1] = ((ull)w[3] << 32) | w[2];
    }
    return f.v;
}

// fast transcendentals: v_rcp_f32 approx (~2 ulp) -- error << bf16 rounding
__device__ __forceinline__ float frcp_(float x) { return __builtin_amdgcn_rcpf(x); }
__device__ __forceinline__ float sigm(float x)  { return frcp_(1.f + __expf(-x)); }
__device__ __forceinline__ float tanhf_(float x){ return 1.f - 2.f * frcp_(1.f + __expf(2.f * x)); }

// ---- ws layout (4-byte units) ----
// proven ws budget: >= 8,016,000 floats. high-water here: 7,589,105.
// lifetimes: bkt1 dies after hopA -> aggb (hopB output) aliases it.
#define OFF_BKT1  0            // u32[2,000,000]; aggb u32[1,600,000] aliases
#define OFF_BKT2  2000000      // u32[2,000,000]
#define OFF_EXB   4000000      // u32[3,200,000] -> ends 7,200,000
#define OFF_FSC   7200000      // int[FCN+1]     -> ends 7,575,361 (scan + sentinel)
#define OFF_TOT   7575361      // int[SCB2=367]  -> ends 7,575,728
#define OFF_BCOMB 7575728      // f32[64]
#define OFF_WIHB  7575792      // u16[12288] (6144 f)
#define OFF_WHHB  7581936      // u16[12288]
#define OFF_WCB   7588080      // u16[2048] (1024 f)
#define OFF_FLAG  7589104      // u32 -> ends 7,589,105

__global__ void detect_kernel(const u32* __restrict__ xw, u32* __restrict__ flag) {
    __shared__ int cnt;
    if (threadIdx.x == 0) cnt = 0;
    __syncthreads();
    int hits = 0;
    for (int i = threadIdx.x; i < 1024; i += 256) {
        float v = bf2f((u16)(xw[i] & 0xffffu));
        if (!(fabsf(v) < 1e10f)) hits++;
    }
    atomicAdd(&cnt, hits);
    __syncthreads();
    if (threadIdx.x == 0) flag[0] = (cnt >= 16) ? 1u : 0u;
}

#define XBASE 26688
__global__ __launch_bounds__(256) void setup_kernel(
        const void* __restrict__ W_conv, const void* __restrict__ b_conv,
        const void* __restrict__ W_mix,  const void* __restrict__ b_mix,
        const void* __restrict__ W_ih,   const void* __restrict__ W_hh,
        float* __restrict__ bcomb, u16* __restrict__ Wihb, u16* __restrict__ Whhb,
        u16* __restrict__ Wcb, const u32* __restrict__ flag) {
    int isf = (int)flag[0];
    int gid = blockIdx.x * 256 + threadIdx.x;
    if (gid < 12288) {
        Wihb[gid] = ldb(W_ih, gid, isf);
    } else if (gid < 24576) {
        int i = gid - 12288;
        Whhb[i] = ldb(W_hh, i, isf);
    } else if (gid < 26624) {
        int i = gid - 24576;
        int j = i >> 5, k = i & 31;
        int t0 = k >> 4, kk = k & 15;
        float acc = 0.f;
        for (int c = 0; c < 64; c++)
            acc += ldv(W_conv, (t0 * 16 + kk) * 64 + c, isf) * ldv(W_mix, (t0 * 64 + c) * 64 + j, isf);
        Wcb[i] = f2bf(acc);
    } else if (gid < XBASE) {
        int j = gid - 26624;
        if (j < 64) {
            float acc = ldv(b_mix, j, isf);
            for (int c = 0; c < 128; c++)
                acc += ldv(b_conv, c, isf) * ldv(W_mix, c * 64 + j, isf);
            bcomb[j] = acc;
        }
    }
}

// per-block coarse histograms, both sides fused. fcnt layout: [bucket][block]
// (side-1 buckets 0..NB1-1, then side-2 buckets). LDS int atomics only.
__global__ __launch_bounds__(1024) void countC(const int* __restrict__ en, const int* __restrict__ eh,
                                               const int* __restrict__ ea, int* __restrict__ fcnt) {
    __shared__ int c[NB1 + NB2];
    int g = blockIdx.x, tid = threadIdx.x;
    for (int i = tid; i < NB1 + NB2; i += 1024) c[i] = 0;
    __syncthreads();
    int s = g * CHK2;
    for (int i = s + tid; i < s + CHK2; i += 1024) {
        int t = ea[i];
        atomicAdd(&c[(t * MHE + eh[i]) >> 9], 1);
        atomicAdd(&c[NB1 + ((t * NN + en[i]) >> 9)], 1);
    }
    __syncthreads();
    for (int b = tid; b < NB1 + NB2; b += 1024) fcnt[b * NCB2 + g] = c[b];
}

// hierarchical exclusive scan of fcnt[FCN] in place
__global__ __launch_bounds__(256) void scanA2(int* __restrict__ a, int* __restrict__ tot) {
    __shared__ int lds[256];
    int g = blockIdx.x, t = threadIdx.x;
    int base = g * 1024 + t * 4;
    int v[4]; int s = 0;
    #pragma unroll
    for (int j = 0; j < 4; j++) { v[j] = (base + j < FCN) ? a[base + j] : 0; s += v[j]; }
    lds[t] = s;
    __syncthreads();
    for (int d = 1; d < 256; d <<= 1) {
        int tmp = (t >= d) ? lds[t - d] : 0;
        __syncthreads();
        lds[t] += tmp;
        __syncthreads();
    }
    int run = lds[t] - s;
    #pragma unroll
    for (int j = 0; j < 4; j++) { if (base + j < FCN) a[base + j] = run; run += v[j]; }
    if (t == 255) tot[g] = lds[255];
}

__global__ __launch_bounds__(1024) void scanB2(int* __restrict__ tot) {
    __shared__ int lds[1024];
    int t = threadIdx.x;
    int v = (t < SCB2) ? tot[t] : 0;
    lds[t] = v;
    __syncthreads();
    for (int d = 1; d < 1024; d <<= 1) {
        int tmp = (t >= d) ? lds[t - d] : 0;
        __syncthreads();
        lds[t] += tmp;
        __syncthreads();
    }
    if (t < SCB2) tot[t] = lds[t] - v;
}

__global__ __launch_bounds__(256) void scanC2(int* __restrict__ a, const int* __restrict__ tot) {
    int g = blockIdx.x, t = threadIdx.x;
    int add = tot[g];
    int base = g * 1024 + t * 4;
    #pragma unroll
    for (int j = 0; j < 4; j++)
        if (base + j < FCN) a[base + j] += add;
    if (g == 0 && t == 0) a[FCN] = 2 * EE;   // sentinel: end of side-2
}

// partition pass: per-block bucket counts derived from fscan DIFFERENCES (the
// count pass is redundant post-scan: cnt = fscan[idx+1]-fscan[idx]). Then
// block-local counting sort in LDS + bucket-run copies to global.
template<int SIDE>
__global__ __launch_bounds__(1024) void placeC(const int* __restrict__ en, const int* __restrict__ eh,
                                               const int* __restrict__ ea, const int* __restrict__ fscan,
                                               u32* __restrict__ bktout) {
    __shared__ u32 sarr[CHK2];       // 25 KB
    __shared__ int sbuf[1024];
    __shared__ int cnt[NB1];
    __shared__ int loff[NB1];
    const int nb = SIDE ? NB2 : NB1;
    const int fbase = SIDE ? NB1 * NCB2 : 0;
    int g = blockIdx.x, tid = threadIdx.x;
    // recover this block's bucket counts from the flat scan (sentinel covers last)
    for (int b = tid; b < nb; b += 1024) {
        int idx = fbase + b * NCB2 + g;
        cnt[b] = fscan[idx + 1] - fscan[idx];
    }
    __syncthreads();
    // LDS exclusive scan of cnt[nb] -> loff
    int v = (tid < nb) ? cnt[tid] : 0;
    sbuf[tid] = v;
    __syncthreads();
    for (int d = 1; d < 1024; d <<= 1) {
        int tmp = (tid >= d) ? sbuf[tid - d] : 0;
        __syncthreads();
        sbuf[tid] += tmp;
        __syncthreads();
    }
    if (tid < nb) { loff[tid] = sbuf[tid] - v; cnt[tid] = 0; }
    __syncthreads();
    // rank + stage into bucket-sorted LDS
    int s = g * CHK2;
    for (int i = s + tid; i < s + CHK2; i += 1024) {
        int t = ea[i]; int nd = en[i]; int hh = eh[i];
        int k = SIDE ? (t * NN + nd) : (t * MHE + hh);
        int b = k >> 9;
        int r = atomicAdd(&cnt[b], 1);
        u32 pay = SIDE ? (((u32)(k & 511) << 19) | (u32)(t * MHE + hh))
                       : (((u32)(k & 511) << 17) | (u32)nd);
        sarr[loff[b] + r] = pay;
    }
    __syncthreads();
    // copy: slot -> bucket via binary search; bucket-runs are contiguous in global
    for (int s2 = tid; s2 < CHK2; s2 += 1024) {
        int lo = 0, hi = nb - 1;
        while (lo < hi) {
            int mid = (lo + hi + 1) >> 1;
            if (loff[mid] <= s2) lo = mid; else hi = mid - 1;
        }
        int gp = fscan[fbase + lo * NCB2 + g] + (s2 - loff[lo]);
        if (SIDE) gp -= EE;
        bktout[gp] = sarr[s2];
    }
}

// hopA: one block per side-1 coarse bucket. Build fine (512-key) CSR in LDS,
// then 8-lane groups aggregate x rows per hedge key in REGISTERS, fold Binv,
// write exb coalesced. No f32 atomics anywhere.
__global__ __launch_bounds__(512) void hopA(const int* __restrict__ fscan, const u32* __restrict__ bkt1,
                                            const void* __restrict__ x, u32* __restrict__ exb,
                                            const u32* __restrict__ flag) {
    __shared__ int fcnt[512], foff[513], sbuf[512];
    __shared__ int snod[CAP1];
    int isf = (int)flag[0];
    int c = blockIdx.x, tid = threadIdx.x;
    int beg = fscan[c * NCB2], end = fscan[(c + 1) * NCB2];
    fcnt[tid] = 0;
    __syncthreads();
    for (int i = beg + tid; i < end; i += 512)
        atomicAdd(&fcnt[bkt1[i] >> 17], 1);
    __syncthreads();
    int v = fcnt[tid];
    sbuf[tid] = v;
    __syncthreads();
    for (int d = 1; d < 512; d <<= 1) {
        int tmp = (tid >= d) ? sbuf[tid - d] : 0;
        __syncthreads();
        sbuf[tid] += tmp;
        __syncthreads();
    }
    foff[tid] = sbuf[tid] - v;
    fcnt[tid] = 0;
    if (tid == 511) foff[512] = sbuf[511];
    __syncthreads();
    for (int i = beg + tid; i < end; i += 512) {
        u32 p = bkt1[i];
        int k = (int)(p >> 17);
        int r = atomicAdd(&fcnt[k], 1);
        snod[foff[k] + r] = (int)(p & 0x1FFFFu);
    }
    __syncthreads();
    int sub = tid & 7, grp = tid >> 3;     // 64 groups of 8 lanes
    for (int kk = grp; kk < 512; kk += 64) {
        int key = c * 512 + kk;
        if (key >= H1) break;
        int fb = foff[kk], fe = foff[kk + 1];
        float a0 = 0.f, a1 = 0.f;
        if (isf) {
            const float* xf = (const float*)x;
            for (int j = fb; j < fe; j++) {
                long n0 = (long)snod[j];
                a0 += xf[n0 * 16 + 2 * sub];
                a1 += xf[n0 * 16 + 2 * sub + 1];
            }
        } else {
            const u32* xu = (const u32*)x;
            for (int j = fb; j < fe; j++) {
                u32 w = xu[(long)snod[j] * 8 + sub];
                a0 += bf2f((u16)(w & 0xffffu));
                a1 += bf2f((u16)(w >> 16));
            }
        }
        int d = fe - fb;
        float inv = d > 0 ? 1.0f / (float)d : 0.f;
        exb[(long)key * 8 + sub] = (u32)f2bf(a0 * inv) | ((u32)f2bf(a1 * inv) << 16);
    }
}

// hopB: one block per side-2 coarse bucket; gather exb rows per node key,
// fold Dinv, write aggb (zeros for deg-0 keys -> no memset needed).
__global__ __launch_bounds__(512) void hopB(const int* __restrict__ fscan, const u32* __restrict__ bkt2,
                                            const u32* __restrict__ exb, u32* __restrict__ aggb) {
    __shared__ int fcnt[512], foff[513], sbuf[512];
    __shared__ int shed[CAP2];
    int c = blockIdx.x, tid = threadIdx.x;
    int beg = fscan[NB1 * NCB2 + c * NCB2] - EE;
    int end = fscan[NB1 * NCB2 + (c + 1) * NCB2] - EE;
    fcnt[tid] = 0;
    __syncthreads();
    for (int i = beg + tid; i < end; i += 512)
        atomicAdd(&fcnt[bkt2[i] >> 19], 1);
    __syncthreads();
    int v = fcnt[tid];
    sbuf[tid] = v;
    __syncthreads();
    for (int d = 1; d < 512; d <<= 1) {
        int tmp = (tid >= d) ? sbuf[tid - d] : 0;
        __syncthreads();
        sbuf[tid] += tmp;
        __syncthreads();
    }
    foff[tid] = sbuf[tid] - v;
    fcnt[tid] = 0;
    if (tid == 511) foff[512] = sbuf[511];
    __syncthreads();
    for (int i = beg + tid; i < end; i += 512) {
        u32 p = bkt2[i];
        int k = (int)(p >> 19);
        int r = atomicAdd(&fcnt[k], 1);
        shed[foff[k] + r] = (int)(p & 0x7FFFFu);
    }
    __syncthreads();
    int sub = tid & 7, grp = tid >> 3;
    for (int kk = grp; kk < 512; kk += 64) {
        int key = c * 512 + kk;
        if (key >= K2N) break;
        int fb = foff[kk], fe = foff[kk + 1];
        float a0 = 0.f, a1 = 0.f;
        for (int j = fb; j < fe; j++) {
            u32 w = exb[(long)shed[j] * 8 + sub];
            a0 += bf2f((u16)(w & 0xffffu));
            a1 += bf2f((u16)(w >> 16));
        }
        int d = fe - fb;
        float inv = d > 0 ? 1.0f / (float)d : 0.f;
        aggb[(long)key * 8 + sub] = (u32)f2bf(a0 * inv) | ((u32)f2bf(a1 * inv) << 16);
    }
}

// MFMA epilogue. Occupancy-tuned: constants in LDS (not 35 VGPRs), c-loop split
// in halves (acc pressure 64->32 VGPRs), fast sigm/tanh, launch_bounds(256,4)
// -> <=128 VGPR -> 4 waves/SIMD (was 176 VGPR / 2 waves).
__global__ __launch_bounds__(256, 4) void epilogue(const u32* __restrict__ aggb,
                                                const float* __restrict__ bcomb,
                                                const u16* __restrict__ Wihb,
                                                const u16* __restrict__ Whhb,
                                                const u16* __restrict__ Wcb,
                                                const void* __restrict__ b_ih, const void* __restrict__ b_hh,
                                                const void* __restrict__ h_prev,
                                                const void* __restrict__ W_out, const void* __restrict__ b_out,
                                                void* __restrict__ out,
                                                const u32* __restrict__ flag) {
    __shared__ u16 hA[4][16][72];
    __shared__ float cb[8][64];    // bc, br, bz, bin, bhn, wo0, wo1, wo2
    __shared__ float cbo[3];
    int isf = (int)flag[0];
    int tid = threadIdx.x;
    if (tid < 64) {
        int j = tid;
        cb[0][j] = bcomb[j];
        cb[1][j] = ldv(b_ih, j, isf)       + ldv(b_hh, j, isf);
        cb[2][j] = ldv(b_ih, 64 + j, isf)  + ldv(b_hh, 64 + j, isf);
        cb[3][j] = ldv(b_ih, 128 + j, isf);
        cb[4][j] = ldv(b_hh, 128 + j, isf);
        cb[5][j] = ldv(W_out, (long)j * 64 + 0, isf);
        cb[6][j] = ldv(W_out, (long)j * 64 + 1, isf);
        cb[7][j] = ldv(W_out, (long)j * 64 + 2, isf);
        if (j < 3) cbo[j] = ldv(b_out, j, isf);
    }
    __syncthreads();
    int w = tid >> 6, lane = tid & 63;
    int cl = lane & 15, q = lane >> 4;
    u16* hAw = &hA[w][0][0];

    for (int wt = blockIdx.x * 4 + w; wt < NN / 16; wt += gridDim.x * 4) {
        long nb = (long)wt * 16;
        {
            int t0 = q >> 1;
            long nidx = nb + cl;
            const u32* ap = aggb + ((long)t0 * NN + nidx) * 8 + (q & 1) * 4;
            u32x4 aw = *(const u32x4*)ap;
            FragU fa;
            fa.q[0] = ((ull)aw[1] << 32) | aw[0];
            fa.q[1] = ((ull)aw[3] << 32) | aw[2];
            #pragma unroll
            for (int c = 0; c < 4; c++) {
                f32x4 hacc = (f32x4){0.f, 0.f, 0.f, 0.f};
                s16x8 bfr = *(const s16x8*)(Wcb + (c * 16 + cl) * 32 + q * 8);
                hacc = __builtin_amdgcn_mfma_f32_16x16x32_bf16(fa.v, bfr, hacc, 0, 0, 0);
                float bc = cb[0][c * 16 + cl];
                #pragma unroll
                for (int reg = 0; reg < 4; reg++) {
                    float hv = fmaxf(hacc[reg] + bc, 0.f);
                    hAw[(q * 4 + reg) * 72 + c * 16 + cl] = f2bf(hv);
                }
            }
        }
        asm volatile("" ::: "memory");   // hA is per-warp: in-order within wave
        const u16* hrow = hAw + cl * 72;
        FragU ha0, ha1;
        #pragma unroll
        for (int j = 0; j < 8; j++) {
            ha0.u[j] = hrow[q * 8 + j];
            ha1.u[j] = hrow[32 + q * 8 + j];
        }
        s16x8 hp0 = ld8bf(h_prev, (nb + cl) * 64 + q * 8, isf);
        s16x8 hp1 = ld8bf(h_prev, (nb + cl) * 64 + 32 + q * 8, isf);

        float p0[4] = {0,0,0,0}, p1[4] = {0,0,0,0}, p2[4] = {0,0,0,0};
        #pragma unroll
        for (int ch = 0; ch < 2; ch++) {
            f32x4 accr[2], accz[2], accin[2], acchn[2];
            #pragma unroll
            for (int cc = 0; cc < 2; cc++) {
                int j = (ch * 2 + cc) * 16 + cl;
                float br_ = cb[1][j], bz_ = cb[2][j], bi_ = cb[3][j], bh_ = cb[4][j];
                accr[cc]  = (f32x4){br_, br_, br_, br_};
                accz[cc]  = (f32x4){bz_, bz_, bz_, bz_};
                accin[cc] = (f32x4){bi_, bi_, bi_, bi_};
                acchn[cc] = (f32x4){bh_, bh_, bh_, bh_};
            }
            #pragma unroll
            for (int s = 0; s < 2; s++) {
                s16x8 hf  = s ? ha1.v : ha0.v;
                s16x8 hpf = s ? hp1 : hp0;
                int ko = s * 32 + q * 8;
                #pragma unroll
                for (int cc = 0; cc < 2; cc++) {
                    int rr = (ch * 2 + cc) * 16 + cl;
                    s16x8 bir  = *(const s16x8*)(Wihb + (long)rr * 64 + ko);
                    s16x8 bhr  = *(const s16x8*)(Whhb + (long)rr * 64 + ko);
                    s16x8 biz  = *(const s16x8*)(Wihb + (long)(64 + rr) * 64 + ko);
                    s16x8 bhz  = *(const s16x8*)(Whhb + (long)(64 + rr) * 64 + ko);
                    s16x8 bin2 = *(const s16x8*)(Wihb + (long)(128 + rr) * 64 + ko);
                    s16x8 bhn2 = *(const s16x8*)(Whhb + (long)(128 + rr) * 64 + ko);
                    accr[cc]  = __builtin_amdgcn_mfma_f32_16x16x32_bf16(hf,  bir,  accr[cc], 0, 0, 0);
                    accr[cc]  = __builtin_amdgcn_mfma_f32_16x16x32_bf16(hpf, bhr,  accr[cc], 0, 0, 0);
                    accz[cc]  = __builtin_amdgcn_mfma_f32_16x16x32_bf16(hf,  biz,  accz[cc], 0, 0, 0);
                    accz[cc]  = __builtin_amdgcn_mfma_f32_16x16x32_bf16(hpf, bhz,  accz[cc], 0, 0, 0);
                    accin[cc] = __builtin_amdgcn_mfma_f32_16x16x32_bf16(hf,  bin2, accin[cc], 0, 0, 0);
                    acchn[cc] = __builtin_amdgcn_mfma_f32_16x16x32_bf16(hpf, bhn2, acchn[cc], 0, 0, 0);
                }
            }
            #pragma unroll
            for (int cc = 0; cc < 2; cc++) {
                int j = (ch * 2 + cc) * 16 + cl;
                float wo0 = cb[5][j], wo1 = cb[6][j], wo2 = cb[7][j];
                #pragma unroll
                for (int reg = 0; reg < 4; reg++) {
                    float rr = sigm(accr[cc][reg]);
                    float zz = sigm(accz[cc][reg]);
                    float ng = tanhf_(accin[cc][reg] + rr * acchn[cc][reg]);
                    long n = nb + q * 4 + reg;
                    float hp = ldv(h_prev, n * 64 + j, isf);
                    float hx = (1.f - zz) * ng + zz * hp;
                    stv(out, n * 64 + j, hx, isf);
                    p0[reg] += hx * wo0;
                    p1[reg] += hx * wo1;
                    p2[reg] += hx * wo2;
                }
            }
        }
        #pragma unroll
        for (int reg = 0; reg < 4; reg++) {
            #pragma unroll
            for (int off2 = 1; off2 < 16; off2 <<= 1) {
                p0[reg] += __shfl_xor(p0[reg], off2);
                p1[reg] += __shfl_xor(p1[reg], off2);
                p2[reg] += __shfl_xor(p2[reg], off2);
            }
        }
        if (cl == 0) {
            #pragma unroll
            for (int reg = 0; reg < 4; reg++) {
                long n = nb + q * 4 + reg;
                long pb = (long)NN * 64 + n * 3;
                stv(out, pb + 0, p0[reg] + cbo[0], isf);
                stv(out, pb + 1, p1[reg] + cbo[1], isf);
                stv(out, pb + 2, p2[reg] + cbo[2], isf);
            }
        }
    }
}

extern "C" void kernel_launch(void* const* d_in, const int* in_sizes, int n_in,
                              void* d_out, int out_size, void* d_ws, size_t ws_size,
                              hipStream_t stream) {
    const void* x      = d_in[0];
    const void* h_prev = d_in[1];
    const int* en      = (const int*)d_in[2];
    const int* eh      = (const int*)d_in[3];
    const int* ea      = (const int*)d_in[4];
    const void* W_conv = d_in[5];
    const void* b_conv = d_in[6];
    const void* W_mix  = d_in[7];
    const void* b_mix  = d_in[8];
    const void* W_ih   = d_in[9];
    const void* W_hh   = d_in[10];
    const void* b_ih   = d_in[11];
    const void* b_hh   = d_in[12];
    const void* W_out  = d_in[13];
    const void* b_out  = d_in[14];
    void* out          = d_out;

    float* ws    = (float*)d_ws;
    u32* bkt1    = (u32*)(ws + OFF_BKT1);
    u32* bkt2    = (u32*)(ws + OFF_BKT2);
    u32* exb     = (u32*)(ws + OFF_EXB);
    int* fscan   = (int*)(ws + OFF_FSC);
    u32* aggb    = (u32*)(ws + OFF_BKT1);   // alias: bkt1 dead after hopA
    float* bcomb = ws + OFF_BCOMB;
    u16* Wihb    = (u16*)(ws + OFF_WIHB);
    u16* Whhb    = (u16*)(ws + OFF_WHHB);
    u16* Wcb     = (u16*)(ws + OFF_WCB);
    u32* flag    = (u32*)(ws + OFF_FLAG);
    int* tot     = (int*)(ws + OFF_TOT);

    detect_kernel<<<1, 256, 0, stream>>>((const u32*)x, flag);
    setup_kernel<<<(XBASE + 255) / 256, 256, 0, stream>>>(
        W_conv, b_conv, W_mix, b_mix, W_ih, W_hh,
        bcomb, Wihb, Whhb, Wcb, flag);
    countC<<<NCB2, 1024, 0, stream>>>(en, eh, ea, fscan);
    scanA2<<<SCB2, 256, 0, stream>>>(fscan, tot);
    scanB2<<<1, 1024, 0, stream>>>(tot);
    scanC2<<<SCB2, 256, 0, stream>>>(fscan, tot);
    placeC<0><<<NCB2, 1024, 0, stream>>>(en, eh, ea, fscan, bkt1);
    placeC<1><<<NCB2, 1024, 0, stream>>>(en, eh, ea, fscan, bkt2);
    hopA<<<NB1, 512, 0, stream>>>(fscan, bkt1, x, exb, flag);
    hopB<<<NB2, 512, 0, stream>>>(fscan, bkt2, exb, aggb);
    epilogue<<<1563, 256, 0, stream>>>(aggb, bcomb, Wihb, Whhb, Wcb,
                                       b_ih, b_hh, h_prev, W_out, b_out, out, flag);
}

// Round 10
// 353.706 us; speedup vs baseline: 1.1165x; 1.1165x over previous
//
#include <hip/hip_runtime.h>

#define NN      100000
#define MHE     200000
#define EE      2000000
#define H1      400000      // hedge keys (2 types)
#define K2N     200000      // node keys (2 types)
#define NB1     782         // side-1 coarse buckets (512 hedge-keys each)
#define NB2     391         // side-2 coarse buckets (512 node-keys each)
#define NCB2    320         // partition blocks
#define CHK2    6250        // edges per partition block (320*6250 = EE exactly)
#define FCN     375360      // (NB1+NB2)*NCB2 flat counters
#define SCB2    367         // ceil(FCN/1024)
#define CAP1    3584        // max items per side-1 bucket (mean 2560)
#define CAP2    6144        // max items per side-2 bucket (mean 5120)

typedef unsigned short u16;
typedef unsigned int   u32;
typedef unsigned long long ull;
typedef __attribute__((ext_vector_type(8))) short  s16x8;
typedef __attribute__((ext_vector_type(4))) float  f32x4;
typedef __attribute__((ext_vector_type(4))) unsigned int u32x4;

__device__ __forceinline__ float bf2f(u16 u) { return __uint_as_float(((u32)u) << 16); }
__device__ __forceinline__ u16 f2bf(float f) {
    u32 u = __float_as_uint(f);
    return (u16)((u + 0x7fffu + ((u >> 16) & 1u)) >> 16);
}
__device__ __forceinline__ float ldv(const void* p, long i, int isf32) {
    return isf32 ? ((const float*)p)[i] : bf2f(((const u16*)p)[i]);
}
__device__ __forceinline__ u16 ldb(const void* p, long i, int isf32) {
    return isf32 ? f2bf(((const float*)p)[i]) : ((const u16*)p)[i];
}
__device__ __forceinline__ void stv(void* p, long i, float v, int isf32) {
    if (isf32) ((float*)p)[i] = v;
    else       ((u16*)p)[i] = f2bf(v);
}

union FragU { s16x8 v; ull q[2]; u16 u[8]; };

__device__ __forceinline__ s16x8 ld8bf(const void* p, long off, int isf32) {
    FragU f;
    if (isf32) {
        const float* fp = (const float*)p + off;
        f32x4 a = *(const f32x4*)fp;
        f32x4 b = *(const f32x4*)(fp + 4);
        f.u[0]=f2bf(a[0]); f.u[1]=f2bf(a[1]); f.u[2]=f2bf(a[2]); f.u[3]=f2bf(a[3]);
        f.u[4]=f2bf(b[0]); f.u[5]=f2bf(b[1]); f.u[6]=f2bf(b[2]); f.u[7]=f2bf(b[3]);
    } else {
        u32x4 w = *(const u32x4*)((const u16*)p + off);
        f.q[0] = ((ull)w[1] << 32) | w[0];
        f.q[1] = ((ull)w[3] << 32) | w[2];
    }
    return f.v;
}

// fast transcendentals: v_rcp_f32 approx (~2 ulp) -- error << bf16 rounding
__device__ __forceinline__ float frcp_(float x) { return __builtin_amdgcn_rcpf(x); }
__device__ __forceinline__ float sigm(float x)  { return frcp_(1.f + __expf(-x)); }
__device__ __forceinline__ float tanhf_(float x){ return 1.f - 2.f * frcp_(1.f + __expf(2.f * x)); }

// ---- ws layout (4-byte units) ----
// proven ws budget: >= 8,016,000 floats. high-water here: 7,589,105.
// lifetimes: bkt1 dies after hopA -> aggb (hopB output) aliases it.
#define OFF_BKT1  0            // u32[2,000,000]; aggb u32[1,600,000] aliases
#define OFF_BKT2  2000000      // u32[2,000,000]
#define OFF_EXB   4000000      // u32[3,200,000] -> ends 7,200,000
#define OFF_FSC   7200000      // int[FCN+1]     -> ends 7,575,361 (scan + sentinel)
#define OFF_TOT   7575361      // int[SCB2=367]  -> ends 7,575,728
#define OFF_BCOMB 7575728      // f32[64]
#define OFF_WIHB  7575792      // u16[12288] (6144 f)
#define OFF_WHHB  7581936      // u16[12288]
#define OFF_WCB   7588080      // u16[2048] (1024 f)
#define OFF_FLAG  7589104      // u32 -> ends 7,589,105

__global__ void detect_kernel(const u32* __restrict__ xw, u32* __restrict__ flag) {
    __shared__ int cnt;
    if (threadIdx.x == 0) cnt = 0;
    __syncthreads();
    int hits = 0;
    for (int i = threadIdx.x; i < 1024; i += 256) {
        float v = bf2f((u16)(xw[i] & 0xffffu));
        if (!(fabsf(v) < 1e10f)) hits++;
    }
    atomicAdd(&cnt, hits);
    __syncthreads();
    if (threadIdx.x == 0) flag[0] = (cnt >= 16) ? 1u : 0u;
}

#define XBASE 26688
__global__ __launch_bounds__(256) void setup_kernel(
        const void* __restrict__ W_conv, const void* __restrict__ b_conv,
        const void* __restrict__ W_mix,  const void* __restrict__ b_mix,
        const void* __restrict__ W_ih,   const void* __restrict__ W_hh,
        float* __restrict__ bcomb, u16* __restrict__ Wihb, u16* __restrict__ Whhb,
        u16* __restrict__ Wcb, const u32* __restrict__ flag) {
    int isf = (int)flag[0];
    int gid = blockIdx.x * 256 + threadIdx.x;
    if (gid < 12288) {
        Wihb[gid] = ldb(W_ih, gid, isf);
    } else if (gid < 24576) {
        int i = gid - 12288;
        Whhb[i] = ldb(W_hh, i, isf);
    } else if (gid < 26624) {
        int i = gid - 24576;
        int j = i >> 5, k = i & 31;
        int t0 = k >> 4, kk = k & 15;
        float acc = 0.f;
        for (int c = 0; c < 64; c++)
            acc += ldv(W_conv, (t0 * 16 + kk) * 64 + c, isf) * ldv(W_mix, (t0 * 64 + c) * 64 + j, isf);
        Wcb[i] = f2bf(acc);
    } else if (gid < XBASE) {
        int j = gid - 26624;
        if (j < 64) {
            float acc = ldv(b_mix, j, isf);
            for (int c = 0; c < 128; c++)
                acc += ldv(b_conv, c, isf) * ldv(W_mix, c * 64 + j, isf);
            bcomb[j] = acc;
        }
    }
}

// per-block coarse histograms, both sides fused. fcnt layout: [bucket][block]
// (side-1 buckets 0..NB1-1, then side-2 buckets). LDS int atomics only.
__global__ __launch_bounds__(1024) void countC(const int* __restrict__ en, const int* __restrict__ eh,
                                               const int* __restrict__ ea, int* __restrict__ fcnt) {
    __shared__ int c[NB1 + NB2];
    int g = blockIdx.x, tid = threadIdx.x;
    for (int i = tid; i < NB1 + NB2; i += 1024) c[i] = 0;
    __syncthreads();
    int s = g * CHK2;
    for (int i = s + tid; i < s + CHK2; i += 1024) {
        int t = ea[i];
        atomicAdd(&c[(t * MHE + eh[i]) >> 9], 1);
        atomicAdd(&c[NB1 + ((t * NN + en[i]) >> 9)], 1);
    }
    __syncthreads();
    for (int b = tid; b < NB1 + NB2; b += 1024) fcnt[b * NCB2 + g] = c[b];
}

// hierarchical exclusive scan of fcnt[FCN] in place
__global__ __launch_bounds__(256) void scanA2(int* __restrict__ a, int* __restrict__ tot) {
    __shared__ int lds[256];
    int g = blockIdx.x, t = threadIdx.x;
    int base = g * 1024 + t * 4;
    int v[4]; int s = 0;
    #pragma unroll
    for (int j = 0; j < 4; j++) { v[j] = (base + j < FCN) ? a[base + j] : 0; s += v[j]; }
    lds[t] = s;
    __syncthreads();
    for (int d = 1; d < 256; d <<= 1) {
        int tmp = (t >= d) ? lds[t - d] : 0;
        __syncthreads();
        lds[t] += tmp;
        __syncthreads();
    }
    int run = lds[t] - s;
    #pragma unroll
    for (int j = 0; j < 4; j++) { if (base + j < FCN) a[base + j] = run; run += v[j]; }
    if (t == 255) tot[g] = lds[255];
}

__global__ __launch_bounds__(1024) void scanB2(int* __restrict__ tot) {
    __shared__ int lds[1024];
    int t = threadIdx.x;
    int v = (t < SCB2) ? tot[t] : 0;
    lds[t] = v;
    __syncthreads();
    for (int d = 1; d < 1024; d <<= 1) {
        int tmp = (t >= d) ? lds[t - d] : 0;
        __syncthreads();
        lds[t] += tmp;
        __syncthreads();
    }
    if (t < SCB2) tot[t] = lds[t] - v;
}

__global__ __launch_bounds__(256) void scanC2(int* __restrict__ a, const int* __restrict__ tot) {
    int g = blockIdx.x, t = threadIdx.x;
    int add = tot[g];
    int base = g * 1024 + t * 4;
    #pragma unroll
    for (int j = 0; j < 4; j++)
        if (base + j < FCN) a[base + j] += add;
    if (g == 0 && t == 0) a[FCN] = 2 * EE;   // sentinel: end of side-2
}

// partition pass: per-block bucket counts derived from fscan DIFFERENCES (the
// count pass is redundant post-scan: cnt = fscan[idx+1]-fscan[idx]). Then
// block-local counting sort in LDS + bucket-run copies to global.
template<int SIDE>
__global__ __launch_bounds__(1024) void placeC(const int* __restrict__ en, const int* __restrict__ eh,
                                               const int* __restrict__ ea, const int* __restrict__ fscan,
                                               u32* __restrict__ bktout) {
    __shared__ u32 sarr[CHK2];       // 25 KB
    __shared__ int sbuf[1024];
    __shared__ int cnt[NB1];
    __shared__ int loff[NB1];
    const int nb = SIDE ? NB2 : NB1;
    const int fbase = SIDE ? NB1 * NCB2 : 0;
    int g = blockIdx.x, tid = threadIdx.x;
    // recover this block's bucket counts from the flat scan (sentinel covers last)
    for (int b = tid; b < nb; b += 1024) {
        int idx = fbase + b * NCB2 + g;
        cnt[b] = fscan[idx + 1] - fscan[idx];
    }
    __syncthreads();
    // LDS exclusive scan of cnt[nb] -> loff
    int v = (tid < nb) ? cnt[tid] : 0;
    sbuf[tid] = v;
    __syncthreads();
    for (int d = 1; d < 1024; d <<= 1) {
        int tmp = (tid >= d) ? sbuf[tid - d] : 0;
        __syncthreads();
        sbuf[tid] += tmp;
        __syncthreads();
    }
    if (tid < nb) { loff[tid] = sbuf[tid] - v; cnt[tid] = 0; }
    __syncthreads();
    // rank + stage into bucket-sorted LDS
    int s = g * CHK2;
    for (int i = s + tid; i < s + CHK2; i += 1024) {
        int t = ea[i]; int nd = en[i]; int hh = eh[i];
        int k = SIDE ? (t * NN + nd) : (t * MHE + hh);
        int b = k >> 9;
        int r = atomicAdd(&cnt[b], 1);
        u32 pay = SIDE ? (((u32)(k & 511) << 19) | (u32)(t * MHE + hh))
                       : (((u32)(k & 511) << 17) | (u32)nd);
        sarr[loff[b] + r] = pay;
    }
    __syncthreads();
    // copy: slot -> bucket via binary search; bucket-runs are contiguous in global
    for (int s2 = tid; s2 < CHK2; s2 += 1024) {
        int lo = 0, hi = nb - 1;
        while (lo < hi) {
            int mid = (lo + hi + 1) >> 1;
            if (loff[mid] <= s2) lo = mid; else hi = mid - 1;
        }
        int gp = fscan[fbase + lo * NCB2 + g] + (s2 - loff[lo]);
        if (SIDE) gp -= EE;
        bktout[gp] = sarr[s2];
    }
}

// hopA: one block per side-1 coarse bucket. Build fine (512-key) CSR in LDS,
// then 8-lane groups aggregate x rows per hedge key in REGISTERS, fold Binv,
// write exb coalesced. No f32 atomics anywhere.
__global__ __launch_bounds__(512) void hopA(const int* __restrict__ fscan, const u32* __restrict__ bkt1,
                                            const void* __restrict__ x, u32* __restrict__ exb,
                                            const u32* __restrict__ flag) {
    __shared__ int fcnt[512], foff[513], sbuf[512];
    __shared__ int snod[CAP1];
    int isf = (int)flag[0];
    int c = blockIdx.x, tid = threadIdx.x;
    int beg = fscan[c * NCB2], end = fscan[(c + 1) * NCB2];
    fcnt[tid] = 0;
    __syncthreads();
    for (int i = beg + tid; i < end; i += 512)
        atomicAdd(&fcnt[bkt1[i] >> 17], 1);
    __syncthreads();
    int v = fcnt[tid];
    sbuf[tid] = v;
    __syncthreads();
    for (int d = 1; d < 512; d <<= 1) {
        int tmp = (tid >= d) ? sbuf[tid - d] : 0;
        __syncthreads();
        sbuf[tid] += tmp;
        __syncthreads();
    }
    foff[tid] = sbuf[tid] - v;
    fcnt[tid] = 0;
    if (tid == 511) foff[512] = sbuf[511];
    __syncthreads();
    for (int i = beg + tid; i < end; i += 512) {
        u32 p = bkt1[i];
        int k = (int)(p >> 17);
        int r = atomicAdd(&fcnt[k], 1);
        snod[foff[k] + r] = (int)(p & 0x1FFFFu);
    }
    __syncthreads();
    int sub = tid & 7, grp = tid >> 3;     // 64 groups of 8 lanes
    for (int kk = grp; kk < 512; kk += 64) {
        int key = c * 512 + kk;
        if (key >= H1) break;
        int fb = foff[kk], fe = foff[kk + 1];
        float a0 = 0.f, a1 = 0.f;
        if (isf) {
            const float* xf = (const float*)x;
            for (int j = fb; j < fe; j++) {
                long n0 = (long)snod[j];
                a0 += xf[n0 * 16 + 2 * sub];
                a1 += xf[n0 * 16 + 2 * sub + 1];
            }
        } else {
            const u32* xu = (const u32*)x;
            for (int j = fb; j < fe; j++) {
                u32 w = xu[(long)snod[j] * 8 + sub];
                a0 += bf2f((u16)(w & 0xffffu));
                a1 += bf2f((u16)(w >> 16));
            }
        }
        int d = fe - fb;
        float inv = d > 0 ? 1.0f / (float)d : 0.f;
        exb[(long)key * 8 + sub] = (u32)f2bf(a0 * inv) | ((u32)f2bf(a1 * inv) << 16);
    }
}

// hopB: one block per side-2 coarse bucket; gather exb rows per node key,
// fold Dinv, write aggb (zeros for deg-0 keys -> no memset needed).
__global__ __launch_bounds__(512) void hopB(const int* __restrict__ fscan, const u32* __restrict__ bkt2,
                                            const u32* __restrict__ exb, u32* __restrict__ aggb) {
    __shared__ int fcnt[512], foff[513], sbuf[512];
    __shared__ int shed[CAP2];
    int c = blockIdx.x, tid = threadIdx.x;
    int beg = fscan[NB1 * NCB2 + c * NCB2] - EE;
    int end = fscan[NB1 * NCB2 + (c + 1) * NCB2] - EE;
    fcnt[tid] = 0;
    __syncthreads();
    for (int i = beg + tid; i < end; i += 512)
        atomicAdd(&fcnt[bkt2[i] >> 19], 1);
    __syncthreads();
    int v = fcnt[tid];
    sbuf[tid] = v;
    __syncthreads();
    for (int d = 1; d < 512; d <<= 1) {
        int tmp = (tid >= d) ? sbuf[tid - d] : 0;
        __syncthreads();
        sbuf[tid] += tmp;
        __syncthreads();
    }
    foff[tid] = sbuf[tid] - v;
    fcnt[tid] = 0;
    if (tid == 511) foff[512] = sbuf[511];
    __syncthreads();
    for (int i = beg + tid; i < end; i += 512) {
        u32 p = bkt2[i];
        int k = (int)(p >> 19);
        int r = atomicAdd(&fcnt[k], 1);
        shed[foff[k] + r] = (int)(p & 0x7FFFFu);
    }
    __syncthreads();
    int sub = tid & 7, grp = tid >> 3;
    for (int kk = grp; kk < 512; kk += 64) {
        int key = c * 512 + kk;
        if (key >= K2N) break;
        int fb = foff[kk], fe = foff[kk + 1];
        float a0 = 0.f, a1 = 0.f;
        for (int j = fb; j < fe; j++) {
            u32 w = exb[(long)shed[j] * 8 + sub];
            a0 += bf2f((u16)(w & 0xffffu));
            a1 += bf2f((u16)(w >> 16));
        }
        int d = fe - fb;
        float inv = d > 0 ? 1.0f / (float)d : 0.f;
        aggb[(long)key * 8 + sub] = (u32)f2bf(a0 * inv) | ((u32)f2bf(a1 * inv) << 16);
    }
}

// MFMA epilogue. Constants in LDS; c-loop split (acc pressure halved); fast
// sigm/tanh. NO forced min-occupancy: round 7's __launch_bounds__(256,4)
// clamped to 64 VGPR -> scratch spills -> +225 MB HBM traffic. Let the
// allocator choose (~110-130 VGPR, no spill); occupancy comes free if <=128.
__global__ __launch_bounds__(256) void epilogue(const u32* __restrict__ aggb,
                                                const float* __restrict__ bcomb,
                                                const u16* __restrict__ Wihb,
                                                const u16* __restrict__ Whhb,
                                                const u16* __restrict__ Wcb,
                                                const void* __restrict__ b_ih, const void* __restrict__ b_hh,
                                                const void* __restrict__ h_prev,
                                                const void* __restrict__ W_out, const void* __restrict__ b_out,
                                                void* __restrict__ out,
                                                const u32* __restrict__ flag) {
    __shared__ u16 hA[4][16][72];
    __shared__ float cb[8][64];    // bc, br, bz, bin, bhn, wo0, wo1, wo2
    __shared__ float cbo[3];
    int isf = (int)flag[0];
    int tid = threadIdx.x;
    if (tid < 64) {
        int j = tid;
        cb[0][j] = bcomb[j];
        cb[1][j] = ldv(b_ih, j, isf)       + ldv(b_hh, j, isf);
        cb[2][j] = ldv(b_ih, 64 + j, isf)  + ldv(b_hh, 64 + j, isf);
        cb[3][j] = ldv(b_ih, 128 + j, isf);
        cb[4][j] = ldv(b_hh, 128 + j, isf);
        cb[5][j] = ldv(W_out, (long)j * 64 + 0, isf);
        cb[6][j] = ldv(W_out, (long)j * 64 + 1, isf);
        cb[7][j] = ldv(W_out, (long)j * 64 + 2, isf);
        if (j < 3) cbo[j] = ldv(b_out, j, isf);
    }
    __syncthreads();
    int w = tid >> 6, lane = tid & 63;
    int cl = lane & 15, q = lane >> 4;
    u16* hAw = &hA[w][0][0];

    for (int wt = blockIdx.x * 4 + w; wt < NN / 16; wt += gridDim.x * 4) {
        long nb = (long)wt * 16;
        {
            int t0 = q >> 1;
            long nidx = nb + cl;
            const u32* ap = aggb + ((long)t0 * NN + nidx) * 8 + (q & 1) * 4;
            u32x4 aw = *(const u32x4*)ap;
            FragU fa;
            fa.q[0] = ((ull)aw[1] << 32) | aw[0];
            fa.q[1] = ((ull)aw[3] << 32) | aw[2];
            #pragma unroll
            for (int c = 0; c < 4; c++) {
                f32x4 hacc = (f32x4){0.f, 0.f, 0.f, 0.f};
                s16x8 bfr = *(const s16x8*)(Wcb + (c * 16 + cl) * 32 + q * 8);
                hacc = __builtin_amdgcn_mfma_f32_16x16x32_bf16(fa.v, bfr, hacc, 0, 0, 0);
                float bc = cb[0][c * 16 + cl];
                #pragma unroll
                for (int reg = 0; reg < 4; reg++) {
                    float hv = fmaxf(hacc[reg] + bc, 0.f);
                    hAw[(q * 4 + reg) * 72 + c * 16 + cl] = f2bf(hv);
                }
            }
        }
        asm volatile("" ::: "memory");   // hA is per-warp: in-order within wave
        const u16* hrow = hAw + cl * 72;
        FragU ha0, ha1;
        #pragma unroll
        for (int j = 0; j < 8; j++) {
            ha0.u[j] = hrow[q * 8 + j];
            ha1.u[j] = hrow[32 + q * 8 + j];
        }
        s16x8 hp0 = ld8bf(h_prev, (nb + cl) * 64 + q * 8, isf);
        s16x8 hp1 = ld8bf(h_prev, (nb + cl) * 64 + 32 + q * 8, isf);

        float p0[4] = {0,0,0,0}, p1[4] = {0,0,0,0}, p2[4] = {0,0,0,0};
        #pragma unroll
        for (int ch = 0; ch < 2; ch++) {
            f32x4 accr[2], accz[2], accin[2], acchn[2];
            #pragma unroll
            for (int cc = 0; cc < 2; cc++) {
                int j = (ch * 2 + cc) * 16 + cl;
                float br_ = cb[1][j], bz_ = cb[2][j], bi_ = cb[3][j], bh_ = cb[4][j];
                accr[cc]  = (f32x4){br_, br_, br_, br_};
                accz[cc]  = (f32x4){bz_, bz_, bz_, bz_};
                accin[cc] = (f32x4){bi_, bi_, bi_, bi_};
                acchn[cc] = (f32x4){bh_, bh_, bh_, bh_};
            }
            #pragma unroll
            for (int s = 0; s < 2; s++) {
                s16x8 hf  = s ? ha1.v : ha0.v;
                s16x8 hpf = s ? hp1 : hp0;
                int ko = s * 32 + q * 8;
                #pragma unroll
                for (int cc = 0; cc < 2; cc++) {
                    int rr = (ch * 2 + cc) * 16 + cl;
                    // interleave load->use pairs to cap live fragments at ~2
                    {
                        s16x8 bir = *(const s16x8*)(Wihb + (long)rr * 64 + ko);
                        accr[cc]  = __builtin_amdgcn_mfma_f32_16x16x32_bf16(hf,  bir,  accr[cc], 0, 0, 0);
                    }
                    {
                        s16x8 bhr = *(const s16x8*)(Whhb + (long)rr * 64 + ko);
                        accr[cc]  = __builtin_amdgcn_mfma_f32_16x16x32_bf16(hpf, bhr,  accr[cc], 0, 0, 0);
                    }
                    {
                        s16x8 biz = *(const s16x8*)(Wihb + (long)(64 + rr) * 64 + ko);
                        accz[cc]  = __builtin_amdgcn_mfma_f32_16x16x32_bf16(hf,  biz,  accz[cc], 0, 0, 0);
                    }
                    {
                        s16x8 bhz = *(const s16x8*)(Whhb + (long)(64 + rr) * 64 + ko);
                        accz[cc]  = __builtin_amdgcn_mfma_f32_16x16x32_bf16(hpf, bhz,  accz[cc], 0, 0, 0);
                    }
                    {
                        s16x8 bin2 = *(const s16x8*)(Wihb + (long)(128 + rr) * 64 + ko);
                        accin[cc] = __builtin_amdgcn_mfma_f32_16x16x32_bf16(hf,  bin2, accin[cc], 0, 0, 0);
                    }
                    {
                        s16x8 bhn2 = *(const s16x8*)(Whhb + (long)(128 + rr) * 64 + ko);
                        acchn[cc] = __builtin_amdgcn_mfma_f32_16x16x32_bf16(hpf, bhn2, acchn[cc], 0, 0, 0);
                    }
                }
            }
            #pragma unroll
            for (int cc = 0; cc < 2; cc++) {
                int j = (ch * 2 + cc) * 16 + cl;
                float wo0 = cb[5][j], wo1 = cb[6][j], wo2 = cb[7][j];
                #pragma unroll
                for (int reg = 0; reg < 4; reg++) {
                    float rr = sigm(accr[cc][reg]);
                    float zz = sigm(accz[cc][reg]);
                    float ng = tanhf_(accin[cc][reg] + rr * acchn[cc][reg]);
                    long n = nb + q * 4 + reg;
                    float hp = ldv(h_prev, n * 64 + j, isf);
                    float hx = (1.f - zz) * ng + zz * hp;
                    stv(out, n * 64 + j, hx, isf);
                    p0[reg] += hx * wo0;
                    p1[reg] += hx * wo1;
                    p2[reg] += hx * wo2;
                }
            }
        }
        #pragma unroll
        for (int reg = 0; reg < 4; reg++) {
            #pragma unroll
            for (int off2 = 1; off2 < 16; off2 <<= 1) {
                p0[reg] += __shfl_xor(p0[reg], off2);
                p1[reg] += __shfl_xor(p1[reg], off2);
                p2[reg] += __shfl_xor(p2[reg], off2);
            }
        }
        if (cl == 0) {
            #pragma unroll
            for (int reg = 0; reg < 4; reg++) {
                long n = nb + q * 4 + reg;
                long pb = (long)NN * 64 + n * 3;
                stv(out, pb + 0, p0[reg] + cbo[0], isf);
                stv(out, pb + 1, p1[reg] + cbo[1], isf);
                stv(out, pb + 2, p2[reg] + cbo[2], isf);
            }
        }
    }
}

extern "C" void kernel_launch(void* const* d_in, const int* in_sizes, int n_in,
                              void* d_out, int out_size, void* d_ws, size_t ws_size,
                              hipStream_t stream) {
    const void* x      = d_in[0];
    const void* h_prev = d_in[1];
    const int* en      = (const int*)d_in[2];
    const int* eh      = (const int*)d_in[3];
    const int* ea      = (const int*)d_in[4];
    const void* W_conv = d_in[5];
    const void* b_conv = d_in[6];
    const void* W_mix  = d_in[7];
    const void* b_mix  = d_in[8];
    const void* W_ih   = d_in[9];
    const void* W_hh   = d_in[10];
    const void* b_ih   = d_in[11];
    const void* b_hh   = d_in[12];
    const void* W_out  = d_in[13];
    const void* b_out  = d_in[14];
    void* out          = d_out;

    float* ws    = (float*)d_ws;
    u32* bkt1    = (u32*)(ws + OFF_BKT1);
    u32* bkt2    = (u32*)(ws + OFF_BKT2);
    u32* exb     = (u32*)(ws + OFF_EXB);
    int* fscan   = (int*)(ws + OFF_FSC);
    u32* aggb    = (u32*)(ws + OFF_BKT1);   // alias: bkt1 dead after hopA
    float* bcomb = ws + OFF_BCOMB;
    u16* Wihb    = (u16*)(ws + OFF_WIHB);
    u16* Whhb    = (u16*)(ws + OFF_WHHB);
    u16* Wcb     = (u16*)(ws + OFF_WCB);
    u32* flag    = (u32*)(ws + OFF_FLAG);
    int* tot     = (int*)(ws + OFF_TOT);

    detect_kernel<<<1, 256, 0, stream>>>((const u32*)x, flag);
    setup_kernel<<<(XBASE + 255) / 256, 256, 0, stream>>>(
        W_conv, b_conv, W_mix, b_mix, W_ih, W_hh,
        bcomb, Wihb, Whhb, Wcb, flag);
    countC<<<NCB2, 1024, 0, stream>>>(en, eh, ea, fscan);
    scanA2<<<SCB2, 256, 0, stream>>>(fscan, tot);
    scanB2<<<1, 1024, 0, stream>>>(tot);
    scanC2<<<SCB2, 256, 0, stream>>>(fscan, tot);
    placeC<0><<<NCB2, 1024, 0, stream>>>(en, eh, ea, fscan, bkt1);
    placeC<1><<<NCB2, 1024, 0, stream>>>(en, eh, ea, fscan, bkt2);
    hopA<<<NB1, 512, 0, stream>>>(fscan, bkt1, x, exb, flag);
    hopB<<<NB2, 512, 0, stream>>>(fscan, bkt2, exb, aggb);
    epilogue<<<1563, 256, 0, stream>>>(aggb, bcomb, Wihb, Whhb, Wcb,
                                       b_ih, b_hh, h_prev, W_out, b_out, out, flag);
}

// Round 11
// 312.154 us; speedup vs baseline: 1.2651x; 1.1331x over previous
//
#include <hip/hip_runtime.h>

#define NN      100000
#define MHE     200000
#define EE      2000000
#define H1      400000      // hedge keys (2 types)
#define K2N     200000      // node keys (2 types)
#define NB1     782         // side-1 coarse buckets (512 hedge-keys each)
#define NB2     391         // side-2 coarse buckets (512 node-keys each)
#define NCB2    320         // partition blocks
#define CHK2    6250        // edges per partition block (320*6250 = EE exactly)
#define FCN     375360      // (NB1+NB2)*NCB2 flat counters
#define SCB2    367         // ceil(FCN/1024)
#define CAP1    3584        // max items per side-1 bucket (mean 2560)
#define CAP2    6144        // max items per side-2 bucket (mean 5120)
#define NT      6250        // epilogue warp-tiles (NN/16)

typedef unsigned short u16;
typedef unsigned int   u32;
typedef unsigned long long ull;
typedef __attribute__((ext_vector_type(8))) short  s16x8;
typedef __attribute__((ext_vector_type(4))) float  f32x4;
typedef __attribute__((ext_vector_type(4))) unsigned int u32x4;

__device__ __forceinline__ float bf2f(u16 u) { return __uint_as_float(((u32)u) << 16); }
__device__ __forceinline__ u16 f2bf(float f) {
    u32 u = __float_as_uint(f);
    return (u16)((u + 0x7fffu + ((u >> 16) & 1u)) >> 16);
}
__device__ __forceinline__ float ldv(const void* p, long i, int isf32) {
    return isf32 ? ((const float*)p)[i] : bf2f(((const u16*)p)[i]);
}
__device__ __forceinline__ u16 ldb(const void* p, long i, int isf32) {
    return isf32 ? f2bf(((const float*)p)[i]) : ((const u16*)p)[i];
}
__device__ __forceinline__ void stv(void* p, long i, float v, int isf32) {
    if (isf32) ((float*)p)[i] = v;
    else       ((u16*)p)[i] = f2bf(v);
}

union FragU { s16x8 v; ull q[2]; u16 u[8]; };

__device__ __forceinline__ s16x8 ld8bf(const void* p, long off, int isf32) {
    FragU f;
    if (isf32) {
        const float* fp = (const float*)p + off;
        f32x4 a = *(const f32x4*)fp;
        f32x4 b = *(const f32x4*)(fp + 4);
        f.u[0]=f2bf(a[0]); f.u[1]=f2bf(a[1]); f.u[2]=f2bf(a[2]); f.u[3]=f2bf(a[3]);
        f.u[4]=f2bf(b[0]); f.u[5]=f2bf(b[1]); f.u[6]=f2bf(b[2]); f.u[7]=f2bf(b[3]);
    } else {
        u32x4 w = *(const u32x4*)((const u16*)p + off);
        f.q[0] = ((ull)w[1] << 32) | w[0];
        f.q[1] = ((ull)w[3] << 32) | w[2];
    }
    return f.v;
}

// fast transcendentals: v_rcp_f32 approx (~2 ulp) -- error << bf16 rounding
__device__ __forceinline__ float frcp_(float x) { return __builtin_amdgcn_rcpf(x); }
__device__ __forceinline__ float sigm(float x)  { return frcp_(1.f + __expf(-x)); }
__device__ __forceinline__ float tanhf_(float x){ return 1.f - 2.f * frcp_(1.f + __expf(2.f * x)); }

// ---- ws layout (4-byte units) ----
// proven ws budget: >= 8,016,000 floats. high-water here: 7,589,105.
// NOTE: Wihb/Whhb/Wcb are CONTIGUOUS (epilogue stages Wihb+Whhb as one 48KB image).
#define OFF_BKT1  0            // u32[2,000,000]; aggb u32[1,600,000] aliases
#define OFF_BKT2  2000000      // u32[2,000,000]
#define OFF_EXB   4000000      // u32[3,200,000] -> ends 7,200,000
#define OFF_FSC   7200000      // int[FCN+1]     -> ends 7,575,361 (scan + sentinel)
#define OFF_TOT   7575361      // int[SCB2=367]  -> ends 7,575,728
#define OFF_BCOMB 7575728      // f32[64]
#define OFF_WIHB  7575792      // u16[12288] (6144 f)
#define OFF_WHHB  7581936      // u16[12288]
#define OFF_WCB   7588080      // u16[2048] (1024 f)
#define OFF_FLAG  7589104      // u32 -> ends 7,589,105

__global__ void detect_kernel(const u32* __restrict__ xw, u32* __restrict__ flag) {
    __shared__ int cnt;
    if (threadIdx.x == 0) cnt = 0;
    __syncthreads();
    int hits = 0;
    for (int i = threadIdx.x; i < 1024; i += 256) {
        float v = bf2f((u16)(xw[i] & 0xffffu));
        if (!(fabsf(v) < 1e10f)) hits++;
    }
    atomicAdd(&cnt, hits);
    __syncthreads();
    if (threadIdx.x == 0) flag[0] = (cnt >= 16) ? 1u : 0u;
}

#define XBASE 26688
__global__ __launch_bounds__(256) void setup_kernel(
        const void* __restrict__ W_conv, const void* __restrict__ b_conv,
        const void* __restrict__ W_mix,  const void* __restrict__ b_mix,
        const void* __restrict__ W_ih,   const void* __restrict__ W_hh,
        float* __restrict__ bcomb, u16* __restrict__ Wihb, u16* __restrict__ Whhb,
        u16* __restrict__ Wcb, const u32* __restrict__ flag) {
    int isf = (int)flag[0];
    int gid = blockIdx.x * 256 + threadIdx.x;
    if (gid < 12288) {
        Wihb[gid] = ldb(W_ih, gid, isf);
    } else if (gid < 24576) {
        int i = gid - 12288;
        Whhb[i] = ldb(W_hh, i, isf);
    } else if (gid < 26624) {
        int i = gid - 24576;
        int j = i >> 5, k = i & 31;
        int t0 = k >> 4, kk = k & 15;
        float acc = 0.f;
        for (int c = 0; c < 64; c++)
            acc += ldv(W_conv, (t0 * 16 + kk) * 64 + c, isf) * ldv(W_mix, (t0 * 64 + c) * 64 + j, isf);
        Wcb[i] = f2bf(acc);
    } else if (gid < XBASE) {
        int j = gid - 26624;
        if (j < 64) {
            float acc = ldv(b_mix, j, isf);
            for (int c = 0; c < 128; c++)
                acc += ldv(b_conv, c, isf) * ldv(W_mix, c * 64 + j, isf);
            bcomb[j] = acc;
        }
    }
}

// per-block coarse histograms, both sides fused. fcnt layout: [bucket][block]
__global__ __launch_bounds__(1024) void countC(const int* __restrict__ en, const int* __restrict__ eh,
                                               const int* __restrict__ ea, int* __restrict__ fcnt) {
    __shared__ int c[NB1 + NB2];
    int g = blockIdx.x, tid = threadIdx.x;
    for (int i = tid; i < NB1 + NB2; i += 1024) c[i] = 0;
    __syncthreads();
    int s = g * CHK2;
    for (int i = s + tid; i < s + CHK2; i += 1024) {
        int t = ea[i];
        atomicAdd(&c[(t * MHE + eh[i]) >> 9], 1);
        atomicAdd(&c[NB1 + ((t * NN + en[i]) >> 9)], 1);
    }
    __syncthreads();
    for (int b = tid; b < NB1 + NB2; b += 1024) fcnt[b * NCB2 + g] = c[b];
}

// hierarchical exclusive scan of fcnt[FCN] in place
__global__ __launch_bounds__(256) void scanA2(int* __restrict__ a, int* __restrict__ tot) {
    __shared__ int lds[256];
    int g = blockIdx.x, t = threadIdx.x;
    int base = g * 1024 + t * 4;
    int v[4]; int s = 0;
    #pragma unroll
    for (int j = 0; j < 4; j++) { v[j] = (base + j < FCN) ? a[base + j] : 0; s += v[j]; }
    lds[t] = s;
    __syncthreads();
    for (int d = 1; d < 256; d <<= 1) {
        int tmp = (t >= d) ? lds[t - d] : 0;
        __syncthreads();
        lds[t] += tmp;
        __syncthreads();
    }
    int run = lds[t] - s;
    #pragma unroll
    for (int j = 0; j < 4; j++) { if (base + j < FCN) a[base + j] = run; run += v[j]; }
    if (t == 255) tot[g] = lds[255];
}

__global__ __launch_bounds__(1024) void scanB2(int* __restrict__ tot) {
    __shared__ int lds[1024];
    int t = threadIdx.x;
    int v = (t < SCB2) ? tot[t] : 0;
    lds[t] = v;
    __syncthreads();
    for (int d = 1; d < 1024; d <<= 1) {
        int tmp = (t >= d) ? lds[t - d] : 0;
        __syncthreads();
        lds[t] += tmp;
        __syncthreads();
    }
    if (t < SCB2) tot[t] = lds[t] - v;
}

__global__ __launch_bounds__(256) void scanC2(int* __restrict__ a, const int* __restrict__ tot) {
    int g = blockIdx.x, t = threadIdx.x;
    int add = tot[g];
    int base = g * 1024 + t * 4;
    #pragma unroll
    for (int j = 0; j < 4; j++)
        if (base + j < FCN) a[base + j] += add;
    if (g == 0 && t == 0) a[FCN] = 2 * EE;   // sentinel: end of side-2
}

// partition pass: bucket counts from fscan DIFFERENCES; block-local counting
// sort in LDS + bucket-run copies to global. No global atomics.
template<int SIDE>
__global__ __launch_bounds__(1024) void placeC(const int* __restrict__ en, const int* __restrict__ eh,
                                               const int* __restrict__ ea, const int* __restrict__ fscan,
                                               u32* __restrict__ bktout) {
    __shared__ u32 sarr[CHK2];       // 25 KB
    __shared__ int sbuf[1024];
    __shared__ int cnt[NB1];
    __shared__ int loff[NB1];
    const int nb = SIDE ? NB2 : NB1;
    const int fbase = SIDE ? NB1 * NCB2 : 0;
    int g = blockIdx.x, tid = threadIdx.x;
    for (int b = tid; b < nb; b += 1024) {
        int idx = fbase + b * NCB2 + g;
        cnt[b] = fscan[idx + 1] - fscan[idx];
    }
    __syncthreads();
    int v = (tid < nb) ? cnt[tid] : 0;
    sbuf[tid] = v;
    __syncthreads();
    for (int d = 1; d < 1024; d <<= 1) {
        int tmp = (tid >= d) ? sbuf[tid - d] : 0;
        __syncthreads();
        sbuf[tid] += tmp;
        __syncthreads();
    }
    if (tid < nb) { loff[tid] = sbuf[tid] - v; cnt[tid] = 0; }
    __syncthreads();
    int s = g * CHK2;
    for (int i = s + tid; i < s + CHK2; i += 1024) {
        int t = ea[i]; int nd = en[i]; int hh = eh[i];
        int k = SIDE ? (t * NN + nd) : (t * MHE + hh);
        int b = k >> 9;
        int r = atomicAdd(&cnt[b], 1);
        u32 pay = SIDE ? (((u32)(k & 511) << 19) | (u32)(t * MHE + hh))
                       : (((u32)(k & 511) << 17) | (u32)nd);
        sarr[loff[b] + r] = pay;
    }
    __syncthreads();
    for (int s2 = tid; s2 < CHK2; s2 += 1024) {
        int lo = 0, hi = nb - 1;
        while (lo < hi) {
            int mid = (lo + hi + 1) >> 1;
            if (loff[mid] <= s2) lo = mid; else hi = mid - 1;
        }
        int gp = fscan[fbase + lo * NCB2 + g] + (s2 - loff[lo]);
        if (SIDE) gp -= EE;
        bktout[gp] = sarr[s2];
    }
}

// hopA: one block per side-1 coarse bucket; fine CSR in LDS + register gather.
__global__ __launch_bounds__(512) void hopA(const int* __restrict__ fscan, const u32* __restrict__ bkt1,
                                            const void* __restrict__ x, u32* __restrict__ exb,
                                            const u32* __restrict__ flag) {
    __shared__ int fcnt[512], foff[513], sbuf[512];
    __shared__ int snod[CAP1];
    int isf = (int)flag[0];
    int c = blockIdx.x, tid = threadIdx.x;
    int beg = fscan[c * NCB2], end = fscan[(c + 1) * NCB2];
    fcnt[tid] = 0;
    __syncthreads();
    for (int i = beg + tid; i < end; i += 512)
        atomicAdd(&fcnt[bkt1[i] >> 17], 1);
    __syncthreads();
    int v = fcnt[tid];
    sbuf[tid] = v;
    __syncthreads();
    for (int d = 1; d < 512; d <<= 1) {
        int tmp = (tid >= d) ? sbuf[tid - d] : 0;
        __syncthreads();
        sbuf[tid] += tmp;
        __syncthreads();
    }
    foff[tid] = sbuf[tid] - v;
    fcnt[tid] = 0;
    if (tid == 511) foff[512] = sbuf[511];
    __syncthreads();
    for (int i = beg + tid; i < end; i += 512) {
        u32 p = bkt1[i];
        int k = (int)(p >> 17);
        int r = atomicAdd(&fcnt[k], 1);
        snod[foff[k] + r] = (int)(p & 0x1FFFFu);
    }
    __syncthreads();
    int sub = tid & 7, grp = tid >> 3;
    for (int kk = grp; kk < 512; kk += 64) {
        int key = c * 512 + kk;
        if (key >= H1) break;
        int fb = foff[kk], fe = foff[kk + 1];
        float a0 = 0.f, a1 = 0.f;
        if (isf) {
            const float* xf = (const float*)x;
            for (int j = fb; j < fe; j++) {
                long n0 = (long)snod[j];
                a0 += xf[n0 * 16 + 2 * sub];
                a1 += xf[n0 * 16 + 2 * sub + 1];
            }
        } else {
            const u32* xu = (const u32*)x;
            for (int j = fb; j < fe; j++) {
                u32 w = xu[(long)snod[j] * 8 + sub];
                a0 += bf2f((u16)(w & 0xffffu));
                a1 += bf2f((u16)(w >> 16));
            }
        }
        int d = fe - fb;
        float inv = d > 0 ? 1.0f / (float)d : 0.f;
        exb[(long)key * 8 + sub] = (u32)f2bf(a0 * inv) | ((u32)f2bf(a1 * inv) << 16);
    }
}

// hopB: one block per side-2 coarse bucket; gather exb rows, fold Dinv.
__global__ __launch_bounds__(512) void hopB(const int* __restrict__ fscan, const u32* __restrict__ bkt2,
                                            const u32* __restrict__ exb, u32* __restrict__ aggb) {
    __shared__ int fcnt[512], foff[513], sbuf[512];
    __shared__ int shed[CAP2];
    int c = blockIdx.x, tid = threadIdx.x;
    int beg = fscan[NB1 * NCB2 + c * NCB2] - EE;
    int end = fscan[NB1 * NCB2 + (c + 1) * NCB2] - EE;
    fcnt[tid] = 0;
    __syncthreads();
    for (int i = beg + tid; i < end; i += 512)
        atomicAdd(&fcnt[bkt2[i] >> 19], 1);
    __syncthreads();
    int v = fcnt[tid];
    sbuf[tid] = v;
    __syncthreads();
    for (int d = 1; d < 512; d <<= 1) {
        int tmp = (tid >= d) ? sbuf[tid - d] : 0;
        __syncthreads();
        sbuf[tid] += tmp;
        __syncthreads();
    }
    foff[tid] = sbuf[tid] - v;
    fcnt[tid] = 0;
    if (tid == 511) foff[512] = sbuf[511];
    __syncthreads();
    for (int i = beg + tid; i < end; i += 512) {
        u32 p = bkt2[i];
        int k = (int)(p >> 19);
        int r = atomicAdd(&fcnt[k], 1);
        shed[foff[k] + r] = (int)(p & 0x7FFFFu);
    }
    __syncthreads();
    int sub = tid & 7, grp = tid >> 3;
    for (int kk = grp; kk < 512; kk += 64) {
        int key = c * 512 + kk;
        if (key >= K2N) break;
        int fb = foff[kk], fe = foff[kk + 1];
        float a0 = 0.f, a1 = 0.f;
        for (int j = fb; j < fe; j++) {
            u32 w = exb[(long)shed[j] * 8 + sub];
            a0 += bf2f((u16)(w & 0xffffu));
            a1 += bf2f((u16)(w >> 16));
        }
        int d = fe - fb;
        float inv = d > 0 ? 1.0f / (float)d : 0.f;
        aggb[(long)key * 8 + sub] = (u32)f2bf(a0 * inv) | ((u32)f2bf(a1 * inv) << 16);
    }
}

// MFMA epilogue v3. Weights (Wih+Whh, 48KB contiguous) staged into LDS once per
// block with 16B-slot XOR swizzle (slot ^= row&7; 16/64/128/192 are 0 mod 8 so
// sl=(s*4+q)^(cl&7) serves all 12 gate reads, 2-way banks = free). Inner loop
// is LDS-only for weights; warps loop ~3 tiles with depth-1 global prefetch of
// aggb + h_prev fragments. Grid 512 = exactly 2 blocks/CU at 60.4KB LDS.
__global__ __launch_bounds__(256) void epilogue(const u32* __restrict__ aggb,
                                                const float* __restrict__ bcomb,
                                                const u16* __restrict__ WihbG,
                                                const u16* __restrict__ Wcb,
                                                const void* __restrict__ b_ih, const void* __restrict__ b_hh,
                                                const void* __restrict__ h_prev,
                                                const void* __restrict__ W_out, const void* __restrict__ b_out,
                                                void* __restrict__ out,
                                                const u32* __restrict__ flag) {
    __shared__ u16 Wl[24576];      // 48KB: rows 0..191 = Wih, 192..383 = Whh (swizzled)
    __shared__ u16 hA[4][16][72];  // 9.2KB
    __shared__ float cb[8][64];    // bc, br, bz, bin, bhn, wo0, wo1, wo2
    __shared__ float cbo[3];
    int isf = (int)flag[0];
    int tid = threadIdx.x;
    // stage weights: 12288 u32, swizzle 16B slot within each 128B row by row&7
    {
        const u32* gw = (const u32*)WihbG;   // Wihb||Whhb contiguous in ws
        for (int i = tid; i < 12288; i += 256) {
            u32 v = gw[i];
            int row = i >> 5;                 // 32 u32 per 128B row
            int wb = (i & 31) * 4;            // byte within row
            int slot = wb >> 4, rem = wb & 15;
            int wb2 = (((slot ^ (row & 7)) << 4) | rem);
            *(u32*)(Wl + ((row << 6) + (wb2 >> 1))) = v;
        }
    }
    if (tid < 64) {
        int j = tid;
        cb[0][j] = bcomb[j];
        cb[1][j] = ldv(b_ih, j, isf)       + ldv(b_hh, j, isf);
        cb[2][j] = ldv(b_ih, 64 + j, isf)  + ldv(b_hh, 64 + j, isf);
        cb[3][j] = ldv(b_ih, 128 + j, isf);
        cb[4][j] = ldv(b_hh, 128 + j, isf);
        cb[5][j] = ldv(W_out, (long)j * 64 + 0, isf);
        cb[6][j] = ldv(W_out, (long)j * 64 + 1, isf);
        cb[7][j] = ldv(W_out, (long)j * 64 + 2, isf);
        if (j < 3) cbo[j] = ldv(b_out, j, isf);
    }
    __syncthreads();
    int w = tid >> 6, lane = tid & 63;
    int cl = lane & 15, q = lane >> 4;
    u16* hAw = &hA[w][0][0];
    int t0 = q >> 1;

    int wt = blockIdx.x * 4 + w;
    const int WSTRIDE = gridDim.x * 4;

    u32x4 aw; s16x8 hpA, hpB;
    if (wt < NT) {
        long nb = (long)wt * 16;
        aw  = *(const u32x4*)(aggb + ((long)t0 * NN + nb + cl) * 8 + (q & 1) * 4);
        hpA = ld8bf(h_prev, (nb + cl) * 64 + q * 8, isf);
        hpB = ld8bf(h_prev, (nb + cl) * 64 + 32 + q * 8, isf);
    }
    while (wt < NT) {
        int cwt = wt;
        u32x4 caw = aw; s16x8 chp0 = hpA, chp1 = hpB;
        wt += WSTRIDE;
        if (wt < NT) {   // depth-1 prefetch of next tile
            long nb = (long)wt * 16;
            aw  = *(const u32x4*)(aggb + ((long)t0 * NN + nb + cl) * 8 + (q & 1) * 4);
            hpA = ld8bf(h_prev, (nb + cl) * 64 + q * 8, isf);
            hpB = ld8bf(h_prev, (nb + cl) * 64 + 32 + q * 8, isf);
        }
        long nb = (long)cwt * 16;
        // ---- stage 1: h = relu(aggb x Wcb + bc) -> hA (bf16) ----
        {
            FragU fa;
            fa.q[0] = ((ull)caw[1] << 32) | caw[0];
            fa.q[1] = ((ull)caw[3] << 32) | caw[2];
            #pragma unroll
            for (int c = 0; c < 4; c++) {
                f32x4 hacc = (f32x4){0.f, 0.f, 0.f, 0.f};
                s16x8 bfr = *(const s16x8*)(Wcb + (c * 16 + cl) * 32 + q * 8);
                hacc = __builtin_amdgcn_mfma_f32_16x16x32_bf16(fa.v, bfr, hacc, 0, 0, 0);
                float bc = cb[0][c * 16 + cl];
                #pragma unroll
                for (int reg = 0; reg < 4; reg++) {
                    float hv = fmaxf(hacc[reg] + bc, 0.f);
                    hAw[(q * 4 + reg) * 72 + c * 16 + cl] = f2bf(hv);
                }
            }
        }
        asm volatile("" ::: "memory");   // hA is per-warp: in-order within wave
        const u16* hrow = hAw + cl * 72;
        FragU ha0, ha1;
        #pragma unroll
        for (int j = 0; j < 8; j++) {
            ha0.u[j] = hrow[q * 8 + j];
            ha1.u[j] = hrow[32 + q * 8 + j];
        }

        float p0[4] = {0,0,0,0}, p1[4] = {0,0,0,0}, p2[4] = {0,0,0,0};
        #pragma unroll
        for (int ch = 0; ch < 2; ch++) {
            f32x4 accr[2], accz[2], accin[2], acchn[2];
            #pragma unroll
            for (int cc = 0; cc < 2; cc++) {
                int j = (ch * 2 + cc) * 16 + cl;
                float br_ = cb[1][j], bz_ = cb[2][j], bi_ = cb[3][j], bh_ = cb[4][j];
                accr[cc]  = (f32x4){br_, br_, br_, br_};
                accz[cc]  = (f32x4){bz_, bz_, bz_, bz_};
                accin[cc] = (f32x4){bi_, bi_, bi_, bi_};
                acchn[cc] = (f32x4){bh_, bh_, bh_, bh_};
            }
            #pragma unroll
            for (int s = 0; s < 2; s++) {
                s16x8 hf  = s ? ha1.v : ha0.v;
                s16x8 hpf = s ? chp1 : chp0;
                int sl8 = ((s * 4 + q) ^ (cl & 7)) * 8;   // swizzled 16B slot
                #pragma unroll
                for (int cc = 0; cc < 2; cc++) {
                    int rr = (ch * 2 + cc) * 16 + cl;
                    const u16* pw = Wl + rr * 64 + sl8;
                    s16x8 bir  = *(const s16x8*)(pw);
                    s16x8 biz  = *(const s16x8*)(pw + 4096);
                    s16x8 bin2 = *(const s16x8*)(pw + 8192);
                    s16x8 bhr  = *(const s16x8*)(pw + 12288);
                    s16x8 bhz  = *(const s16x8*)(pw + 16384);
                    s16x8 bhn2 = *(const s16x8*)(pw + 20480);
                    accr[cc]  = __builtin_amdgcn_mfma_f32_16x16x32_bf16(hf,  bir,  accr[cc], 0, 0, 0);
                    accr[cc]  = __builtin_amdgcn_mfma_f32_16x16x32_bf16(hpf, bhr,  accr[cc], 0, 0, 0);
                    accz[cc]  = __builtin_amdgcn_mfma_f32_16x16x32_bf16(hf,  biz,  accz[cc], 0, 0, 0);
                    accz[cc]  = __builtin_amdgcn_mfma_f32_16x16x32_bf16(hpf, bhz,  accz[cc], 0, 0, 0);
                    accin[cc] = __builtin_amdgcn_mfma_f32_16x16x32_bf16(hf,  bin2, accin[cc], 0, 0, 0);
                    acchn[cc] = __builtin_amdgcn_mfma_f32_16x16x32_bf16(hpf, bhn2, acchn[cc], 0, 0, 0);
                }
            }
            #pragma unroll
            for (int cc = 0; cc < 2; cc++) {
                int j = (ch * 2 + cc) * 16 + cl;
                float wo0 = cb[5][j], wo1 = cb[6][j], wo2 = cb[7][j];
                #pragma unroll
                for (int reg = 0; reg < 4; reg++) {
                    float rr = sigm(accr[cc][reg]);
                    float zz = sigm(accz[cc][reg]);
                    float ng = tanhf_(accin[cc][reg] + rr * acchn[cc][reg]);
                    long n = nb + q * 4 + reg;
                    float hp = ldv(h_prev, n * 64 + j, isf);
                    float hx = (1.f - zz) * ng + zz * hp;
                    stv(out, n * 64 + j, hx, isf);
                    p0[reg] += hx * wo0;
                    p1[reg] += hx * wo1;
                    p2[reg] += hx * wo2;
                }
            }
        }
        #pragma unroll
        for (int reg = 0; reg < 4; reg++) {
            #pragma unroll
            for (int off2 = 1; off2 < 16; off2 <<= 1) {
                p0[reg] += __shfl_xor(p0[reg], off2);
                p1[reg] += __shfl_xor(p1[reg], off2);
                p2[reg] += __shfl_xor(p2[reg], off2);
            }
        }
        if (cl == 0) {
            #pragma unroll
            for (int reg = 0; reg < 4; reg++) {
                long n = nb + q * 4 + reg;
                long pb = (long)NN * 64 + n * 3;
                stv(out, pb + 0, p0[reg] + cbo[0], isf);
                stv(out, pb + 1, p1[reg] + cbo[1], isf);
                stv(out, pb + 2, p2[reg] + cbo[2], isf);
            }
        }
    }
}

extern "C" void kernel_launch(void* const* d_in, const int* in_sizes, int n_in,
                              void* d_out, int out_size, void* d_ws, size_t ws_size,
                              hipStream_t stream) {
    const void* x      = d_in[0];
    const void* h_prev = d_in[1];
    const int* en      = (const int*)d_in[2];
    const int* eh      = (const int*)d_in[3];
    const int* ea      = (const int*)d_in[4];
    const void* W_conv = d_in[5];
    const void* b_conv = d_in[6];
    const void* W_mix  = d_in[7];
    const void* b_mix  = d_in[8];
    const void* W_ih   = d_in[9];
    const void* W_hh   = d_in[10];
    const void* b_ih   = d_in[11];
    const void* b_hh   = d_in[12];
    const void* W_out  = d_in[13];
    const void* b_out  = d_in[14];
    void* out          = d_out;

    float* ws    = (float*)d_ws;
    u32* bkt1    = (u32*)(ws + OFF_BKT1);
    u32* bkt2    = (u32*)(ws + OFF_BKT2);
    u32* exb     = (u32*)(ws + OFF_EXB);
    int* fscan   = (int*)(ws + OFF_FSC);
    u32* aggb    = (u32*)(ws + OFF_BKT1);   // alias: bkt1 dead after hopA
    float* bcomb = ws + OFF_BCOMB;
    u16* Wihb    = (u16*)(ws + OFF_WIHB);
    u16* Whhb    = (u16*)(ws + OFF_WHHB);
    u16* Wcb     = (u16*)(ws + OFF_WCB);
    u32* flag    = (u32*)(ws + OFF_FLAG);
    int* tot     = (int*)(ws + OFF_TOT);

    detect_kernel<<<1, 256, 0, stream>>>((const u32*)x, flag);
    setup_kernel<<<(XBASE + 255) / 256, 256, 0, stream>>>(
        W_conv, b_conv, W_mix, b_mix, W_ih, W_hh,
        bcomb, Wihb, Whhb, Wcb, flag);
    countC<<<NCB2, 1024, 0, stream>>>(en, eh, ea, fscan);
    scanA2<<<SCB2, 256, 0, stream>>>(fscan, tot);
    scanB2<<<1, 1024, 0, stream>>>(tot);
    scanC2<<<SCB2, 256, 0, stream>>>(fscan, tot);
    placeC<0><<<NCB2, 1024, 0, stream>>>(en, eh, ea, fscan, bkt1);
    placeC<1><<<NCB2, 1024, 0, stream>>>(en, eh, ea, fscan, bkt2);
    hopA<<<NB1, 512, 0, stream>>>(fscan, bkt1, x, exb, flag);
    hopB<<<NB2, 512, 0, stream>>>(fscan, bkt2, exb, aggb);
    epilogue<<<512, 256, 0, stream>>>(aggb, bcomb, Wihb, Wcb,
                                      b_ih, b_hh, h_prev, W_out, b_out, out, flag);
}

// Round 12
// 291.464 us; speedup vs baseline: 1.3550x; 1.0710x over previous
//
#include <hip/hip_runtime.h>

#define NN      100000
#define MHE     200000
#define EE      2000000
#define H1      400000      // hedge keys (2 types)
#define K2N     200000      // node keys (2 types)
#define NB1     782         // side-1 coarse buckets (512 hedge-keys each)
#define NB2     782         // side-2 coarse buckets (256 node-keys each)
#define NCB2    320         // partition blocks
#define CHK2    6250        // edges per partition block (320*6250 = EE exactly)
#define FCN     500480      // (NB1+NB2)*NCB2 flat counters
#define SCB2    489         // ceil(FCN/1024)
#define CAP1    3584        // max items per side-1 bucket (mean 2560)
#define CAP2    3584        // max items per side-2 bucket (mean 2560)
#define NT      6250        // epilogue warp-tiles (NN/16)

typedef unsigned short u16;
typedef unsigned int   u32;
typedef unsigned long long ull;
typedef __attribute__((ext_vector_type(8))) short  s16x8;
typedef __attribute__((ext_vector_type(4))) float  f32x4;
typedef __attribute__((ext_vector_type(4))) unsigned int u32x4;

__device__ __forceinline__ float bf2f(u16 u) { return __uint_as_float(((u32)u) << 16); }
__device__ __forceinline__ u16 f2bf(float f) {
    u32 u = __float_as_uint(f);
    return (u16)((u + 0x7fffu + ((u >> 16) & 1u)) >> 16);
}
__device__ __forceinline__ float ldv(const void* p, long i, int isf32) {
    return isf32 ? ((const float*)p)[i] : bf2f(((const u16*)p)[i]);
}
__device__ __forceinline__ u16 ldb(const void* p, long i, int isf32) {
    return isf32 ? f2bf(((const float*)p)[i]) : ((const u16*)p)[i];
}
__device__ __forceinline__ void stv(void* p, long i, float v, int isf32) {
    if (isf32) ((float*)p)[i] = v;
    else       ((u16*)p)[i] = f2bf(v);
}

union FragU { s16x8 v; ull q[2]; u16 u[8]; };

__device__ __forceinline__ s16x8 ld8bf(const void* p, long off, int isf32) {
    FragU f;
    if (isf32) {
        const float* fp = (const float*)p + off;
        f32x4 a = *(const f32x4*)fp;
        f32x4 b = *(const f32x4*)(fp + 4);
        f.u[0]=f2bf(a[0]); f.u[1]=f2bf(a[1]); f.u[2]=f2bf(a[2]); f.u[3]=f2bf(a[3]);
        f.u[4]=f2bf(b[0]); f.u[5]=f2bf(b[1]); f.u[6]=f2bf(b[2]); f.u[7]=f2bf(b[3]);
    } else {
        u32x4 w = *(const u32x4*)((const u16*)p + off);
        f.q[0] = ((ull)w[1] << 32) | w[0];
        f.q[1] = ((ull)w[3] << 32) | w[2];
    }
    return f.v;
}

// fast transcendentals: v_rcp_f32 approx (~2 ulp) -- error << bf16 rounding
__device__ __forceinline__ float frcp_(float x) { return __builtin_amdgcn_rcpf(x); }
__device__ __forceinline__ float sigm(float x)  { return frcp_(1.f + __expf(-x)); }
__device__ __forceinline__ float tanhf_(float x){ return 1.f - 2.f * frcp_(1.f + __expf(2.f * x)); }

// ---- ws layout (4-byte units) ----
// proven ws budget: >= 8,016,000 floats. high-water here: 7,714,347.
// NOTE: Wihb/Whhb/Wcb are CONTIGUOUS (epilogue stages Wihb+Whhb as one 48KB image).
#define OFF_BKT1  0            // u32[2,000,000]; aggb u32[1,600,000] aliases
#define OFF_BKT2  2000000      // u32[2,000,000]
#define OFF_EXB   4000000      // u32[3,200,000] -> ends 7,200,000
#define OFF_FSC   7200000      // int[FCN+1]     -> ends 7,700,481 (scan + sentinel)
#define OFF_TOT   7700481      // int[SCB2=489]  -> ends 7,700,970
#define OFF_BCOMB 7700970      // f32[64]
#define OFF_WIHB  7701034      // u16[12288] (6144 f)
#define OFF_WHHB  7707178      // u16[12288]
#define OFF_WCB   7713322      // u16[2048] (1024 f)
#define OFF_FLAG  7714346      // u32 -> ends 7,714,347

__global__ void detect_kernel(const u32* __restrict__ xw, u32* __restrict__ flag) {
    __shared__ int cnt;
    if (threadIdx.x == 0) cnt = 0;
    __syncthreads();
    int hits = 0;
    for (int i = threadIdx.x; i < 1024; i += 256) {
        float v = bf2f((u16)(xw[i] & 0xffffu));
        if (!(fabsf(v) < 1e10f)) hits++;
    }
    atomicAdd(&cnt, hits);
    __syncthreads();
    if (threadIdx.x == 0) flag[0] = (cnt >= 16) ? 1u : 0u;
}

#define XBASE 26688
__global__ __launch_bounds__(256) void setup_kernel(
        const void* __restrict__ W_conv, const void* __restrict__ b_conv,
        const void* __restrict__ W_mix,  const void* __restrict__ b_mix,
        const void* __restrict__ W_ih,   const void* __restrict__ W_hh,
        float* __restrict__ bcomb, u16* __restrict__ Wihb, u16* __restrict__ Whhb,
        u16* __restrict__ Wcb, const u32* __restrict__ flag) {
    int isf = (int)flag[0];
    int gid = blockIdx.x * 256 + threadIdx.x;
    if (gid < 12288) {
        Wihb[gid] = ldb(W_ih, gid, isf);
    } else if (gid < 24576) {
        int i = gid - 12288;
        Whhb[i] = ldb(W_hh, i, isf);
    } else if (gid < 26624) {
        int i = gid - 24576;
        int j = i >> 5, k = i & 31;
        int t0 = k >> 4, kk = k & 15;
        float acc = 0.f;
        for (int c = 0; c < 64; c++)
            acc += ldv(W_conv, (t0 * 16 + kk) * 64 + c, isf) * ldv(W_mix, (t0 * 64 + c) * 64 + j, isf);
        Wcb[i] = f2bf(acc);
    } else if (gid < XBASE) {
        int j = gid - 26624;
        if (j < 64) {
            float acc = ldv(b_mix, j, isf);
            for (int c = 0; c < 128; c++)
                acc += ldv(b_conv, c, isf) * ldv(W_mix, c * 64 + j, isf);
            bcomb[j] = acc;
        }
    }
}

// per-block coarse histograms, both sides fused. fcnt layout: [bucket][block]
// side-1 buckets 512-keys wide (>>9), side-2 buckets 256-keys wide (>>8).
__global__ __launch_bounds__(1024) void countC(const int* __restrict__ en, const int* __restrict__ eh,
                                               const int* __restrict__ ea, int* __restrict__ fcnt) {
    __shared__ int c[NB1 + NB2];
    int g = blockIdx.x, tid = threadIdx.x;
    for (int i = tid; i < NB1 + NB2; i += 1024) c[i] = 0;
    __syncthreads();
    int s = g * CHK2;
    for (int i = s + tid; i < s + CHK2; i += 1024) {
        int t = ea[i];
        atomicAdd(&c[(t * MHE + eh[i]) >> 9], 1);
        atomicAdd(&c[NB1 + ((t * NN + en[i]) >> 8)], 1);
    }
    __syncthreads();
    for (int b = tid; b < NB1 + NB2; b += 1024) fcnt[b * NCB2 + g] = c[b];
}

// hierarchical exclusive scan of fcnt[FCN] in place
__global__ __launch_bounds__(256) void scanA2(int* __restrict__ a, int* __restrict__ tot) {
    __shared__ int lds[256];
    int g = blockIdx.x, t = threadIdx.x;
    int base = g * 1024 + t * 4;
    int v[4]; int s = 0;
    #pragma unroll
    for (int j = 0; j < 4; j++) { v[j] = (base + j < FCN) ? a[base + j] : 0; s += v[j]; }
    lds[t] = s;
    __syncthreads();
    for (int d = 1; d < 256; d <<= 1) {
        int tmp = (t >= d) ? lds[t - d] : 0;
        __syncthreads();
        lds[t] += tmp;
        __syncthreads();
    }
    int run = lds[t] - s;
    #pragma unroll
    for (int j = 0; j < 4; j++) { if (base + j < FCN) a[base + j] = run; run += v[j]; }
    if (t == 255) tot[g] = lds[255];
}

__global__ __launch_bounds__(1024) void scanB2(int* __restrict__ tot) {
    __shared__ int lds[1024];
    int t = threadIdx.x;
    int v = (t < SCB2) ? tot[t] : 0;
    lds[t] = v;
    __syncthreads();
    for (int d = 1; d < 1024; d <<= 1) {
        int tmp = (t >= d) ? lds[t - d] : 0;
        __syncthreads();
        lds[t] += tmp;
        __syncthreads();
    }
    if (t < SCB2) tot[t] = lds[t] - v;
}

__global__ __launch_bounds__(256) void scanC2(int* __restrict__ a, const int* __restrict__ tot) {
    int g = blockIdx.x, t = threadIdx.x;
    int add = tot[g];
    int base = g * 1024 + t * 4;
    #pragma unroll
    for (int j = 0; j < 4; j++)
        if (base + j < FCN) a[base + j] += add;
    if (g == 0 && t == 0) a[FCN] = 2 * EE;   // sentinel: end of side-2
}

// partition pass: bucket counts from fscan DIFFERENCES; block-local counting
// sort in LDS + bucket-run copies to global. No global atomics.
template<int SIDE>
__global__ __launch_bounds__(1024) void placeC(const int* __restrict__ en, const int* __restrict__ eh,
                                               const int* __restrict__ ea, const int* __restrict__ fscan,
                                               u32* __restrict__ bktout) {
    __shared__ u32 sarr[CHK2];       // 25 KB
    __shared__ int sbuf[1024];
    __shared__ int cnt[NB1];
    __shared__ int loff[NB1];
    const int nb = SIDE ? NB2 : NB1;
    const int fbase = SIDE ? NB1 * NCB2 : 0;
    int g = blockIdx.x, tid = threadIdx.x;
    for (int b = tid; b < nb; b += 1024) {
        int idx = fbase + b * NCB2 + g;
        cnt[b] = fscan[idx + 1] - fscan[idx];
    }
    __syncthreads();
    int v = (tid < nb) ? cnt[tid] : 0;
    sbuf[tid] = v;
    __syncthreads();
    for (int d = 1; d < 1024; d <<= 1) {
        int tmp = (tid >= d) ? sbuf[tid - d] : 0;
        __syncthreads();
        sbuf[tid] += tmp;
        __syncthreads();
    }
    if (tid < nb) { loff[tid] = sbuf[tid] - v; cnt[tid] = 0; }
    __syncthreads();
    int s = g * CHK2;
    for (int i = s + tid; i < s + CHK2; i += 1024) {
        int t = ea[i]; int nd = en[i]; int hh = eh[i];
        int k = SIDE ? (t * NN + nd) : (t * MHE + hh);
        int b = SIDE ? (k >> 8) : (k >> 9);
        int r = atomicAdd(&cnt[b], 1);
        u32 pay = SIDE ? (((u32)(k & 255) << 19) | (u32)(t * MHE + hh))
                       : (((u32)(k & 511) << 17) | (u32)nd);
        sarr[loff[b] + r] = pay;
    }
    __syncthreads();
    for (int s2 = tid; s2 < CHK2; s2 += 1024) {
        int lo = 0, hi = nb - 1;
        while (lo < hi) {
            int mid = (lo + hi + 1) >> 1;
            if (loff[mid] <= s2) lo = mid; else hi = mid - 1;
        }
        int gp = fscan[fbase + lo * NCB2 + g] + (s2 - loff[lo]);
        if (SIDE) gp -= EE;
        bktout[gp] = sarr[s2];
    }
}

// hopA: one block per side-1 coarse bucket; fine CSR in LDS + register gather,
// gather loop UNROLLED x4 (4 concurrent line fetches per lane).
__global__ __launch_bounds__(512) void hopA(const int* __restrict__ fscan, const u32* __restrict__ bkt1,
                                            const void* __restrict__ x, u32* __restrict__ exb,
                                            const u32* __restrict__ flag) {
    __shared__ int fcnt[512], foff[513], sbuf[512];
    __shared__ int snod[CAP1];
    int isf = (int)flag[0];
    int c = blockIdx.x, tid = threadIdx.x;
    int beg = fscan[c * NCB2], end = fscan[(c + 1) * NCB2];
    fcnt[tid] = 0;
    __syncthreads();
    for (int i = beg + tid; i < end; i += 512)
        atomicAdd(&fcnt[bkt1[i] >> 17], 1);
    __syncthreads();
    int v = fcnt[tid];
    sbuf[tid] = v;
    __syncthreads();
    for (int d = 1; d < 512; d <<= 1) {
        int tmp = (tid >= d) ? sbuf[tid - d] : 0;
        __syncthreads();
        sbuf[tid] += tmp;
        __syncthreads();
    }
    foff[tid] = sbuf[tid] - v;
    fcnt[tid] = 0;
    if (tid == 511) foff[512] = sbuf[511];
    __syncthreads();
    for (int i = beg + tid; i < end; i += 512) {
        u32 p = bkt1[i];
        int k = (int)(p >> 17);
        int r = atomicAdd(&fcnt[k], 1);
        snod[foff[k] + r] = (int)(p & 0x1FFFFu);
    }
    __syncthreads();
    int sub = tid & 7, grp = tid >> 3;
    for (int kk = grp; kk < 512; kk += 64) {
        int key = c * 512 + kk;
        if (key >= H1) break;
        int fb = foff[kk], fe = foff[kk + 1];
        float a0 = 0.f, a1 = 0.f, b0 = 0.f, b1 = 0.f;
        float c0 = 0.f, c1 = 0.f, d0 = 0.f, d1 = 0.f;
        int j = fb;
        if (isf) {
            const float* xf = (const float*)x;
            for (; j + 3 < fe; j += 4) {
                long n0 = (long)snod[j], n1 = (long)snod[j+1];
                long n2 = (long)snod[j+2], n3 = (long)snod[j+3];
                a0 += xf[n0 * 16 + 2 * sub]; a1 += xf[n0 * 16 + 2 * sub + 1];
                b0 += xf[n1 * 16 + 2 * sub]; b1 += xf[n1 * 16 + 2 * sub + 1];
                c0 += xf[n2 * 16 + 2 * sub]; c1 += xf[n2 * 16 + 2 * sub + 1];
                d0 += xf[n3 * 16 + 2 * sub]; d1 += xf[n3 * 16 + 2 * sub + 1];
            }
            for (; j < fe; j++) {
                long n0 = (long)snod[j];
                a0 += xf[n0 * 16 + 2 * sub];
                a1 += xf[n0 * 16 + 2 * sub + 1];
            }
        } else {
            const u32* xu = (const u32*)x;
            for (; j + 3 < fe; j += 4) {
                u32 w0 = xu[(long)snod[j]   * 8 + sub];
                u32 w1 = xu[(long)snod[j+1] * 8 + sub];
                u32 w2 = xu[(long)snod[j+2] * 8 + sub];
                u32 w3 = xu[(long)snod[j+3] * 8 + sub];
                a0 += bf2f((u16)(w0 & 0xffffu)); a1 += bf2f((u16)(w0 >> 16));
                b0 += bf2f((u16)(w1 & 0xffffu)); b1 += bf2f((u16)(w1 >> 16));
                c0 += bf2f((u16)(w2 & 0xffffu)); c1 += bf2f((u16)(w2 >> 16));
                d0 += bf2f((u16)(w3 & 0xffffu)); d1 += bf2f((u16)(w3 >> 16));
            }
            for (; j < fe; j++) {
                u32 w = xu[(long)snod[j] * 8 + sub];
                a0 += bf2f((u16)(w & 0xffffu));
                a1 += bf2f((u16)(w >> 16));
            }
        }
        float s0 = (a0 + b0) + (c0 + d0);
        float s1 = (a1 + b1) + (c1 + d1);
        int d = fe - fb;
        float inv = d > 0 ? 1.0f / (float)d : 0.f;
        exb[(long)key * 8 + sub] = (u32)f2bf(s0 * inv) | ((u32)f2bf(s1 * inv) << 16);
    }
}

// hopB: one block (256 thr) per 256-key side-2 bucket; fine CSR in LDS,
// gather loop UNROLLED x4. Doubled block count for balance/occupancy.
__global__ __launch_bounds__(256) void hopB(const int* __restrict__ fscan, const u32* __restrict__ bkt2,
                                            const u32* __restrict__ exb, u32* __restrict__ aggb) {
    __shared__ int fcnt[256], foff[257], sbuf[256];
    __shared__ int shed[CAP2];
    int c = blockIdx.x, tid = threadIdx.x;
    int beg = fscan[NB1 * NCB2 + c * NCB2] - EE;
    int end = fscan[NB1 * NCB2 + (c + 1) * NCB2] - EE;
    fcnt[tid] = 0;
    __syncthreads();
    for (int i = beg + tid; i < end; i += 256)
        atomicAdd(&fcnt[bkt2[i] >> 19], 1);
    __syncthreads();
    int v = fcnt[tid];
    sbuf[tid] = v;
    __syncthreads();
    for (int d = 1; d < 256; d <<= 1) {
        int tmp = (tid >= d) ? sbuf[tid - d] : 0;
        __syncthreads();
        sbuf[tid] += tmp;
        __syncthreads();
    }
    foff[tid] = sbuf[tid] - v;
    fcnt[tid] = 0;
    if (tid == 255) foff[256] = sbuf[255];
    __syncthreads();
    for (int i = beg + tid; i < end; i += 256) {
        u32 p = bkt2[i];
        int k = (int)(p >> 19);
        int r = atomicAdd(&fcnt[k], 1);
        shed[foff[k] + r] = (int)(p & 0x7FFFFu);
    }
    __syncthreads();
    int sub = tid & 7, grp = tid >> 3;   // 32 groups of 8 lanes
    for (int kk = grp; kk < 256; kk += 32) {
        int key = c * 256 + kk;
        if (key >= K2N) break;
        int fb = foff[kk], fe = foff[kk + 1];
        float a0 = 0.f, a1 = 0.f, b0 = 0.f, b1 = 0.f;
        float c0 = 0.f, c1 = 0.f, d0 = 0.f, d1 = 0.f;
        int j = fb;
        for (; j + 3 < fe; j += 4) {
            u32 w0 = exb[(long)shed[j]   * 8 + sub];
            u32 w1 = exb[(long)shed[j+1] * 8 + sub];
            u32 w2 = exb[(long)shed[j+2] * 8 + sub];
            u32 w3 = exb[(long)shed[j+3] * 8 + sub];
            a0 += bf2f((u16)(w0 & 0xffffu)); a1 += bf2f((u16)(w0 >> 16));
            b0 += bf2f((u16)(w1 & 0xffffu)); b1 += bf2f((u16)(w1 >> 16));
            c0 += bf2f((u16)(w2 & 0xffffu)); c1 += bf2f((u16)(w2 >> 16));
            d0 += bf2f((u16)(w3 & 0xffffu)); d1 += bf2f((u16)(w3 >> 16));
        }
        for (; j < fe; j++) {
            u32 w = exb[(long)shed[j] * 8 + sub];
            a0 += bf2f((u16)(w & 0xffffu));
            a1 += bf2f((u16)(w >> 16));
        }
        float s0 = (a0 + b0) + (c0 + d0);
        float s1 = (a1 + b1) + (c1 + d1);
        int d = fe - fb;
        float inv = d > 0 ? 1.0f / (float)d : 0.f;
        aggb[(long)key * 8 + sub] = (u32)f2bf(s0 * inv) | ((u32)f2bf(s1 * inv) << 16);
    }
}

// MFMA epilogue v3 (round-11 measured-good): weights in LDS (XOR-swizzled),
// multi-tile warps with depth-1 prefetch, grid 512.
__global__ __launch_bounds__(256) void epilogue(const u32* __restrict__ aggb,
                                                const float* __restrict__ bcomb,
                                                const u16* __restrict__ WihbG,
                                                const u16* __restrict__ Wcb,
                                                const void* __restrict__ b_ih, const void* __restrict__ b_hh,
                                                const void* __restrict__ h_prev,
                                                const void* __restrict__ W_out, const void* __restrict__ b_out,
                                                void* __restrict__ out,
                                                const u32* __restrict__ flag) {
    __shared__ u16 Wl[24576];      // 48KB: rows 0..191 = Wih, 192..383 = Whh (swizzled)
    __shared__ u16 hA[4][16][72];  // 9.2KB
    __shared__ float cb[8][64];    // bc, br, bz, bin, bhn, wo0, wo1, wo2
    __shared__ float cbo[3];
    int isf = (int)flag[0];
    int tid = threadIdx.x;
    {
        const u32* gw = (const u32*)WihbG;   // Wihb||Whhb contiguous in ws
        for (int i = tid; i < 12288; i += 256) {
            u32 v = gw[i];
            int row = i >> 5;
            int wb = (i & 31) * 4;
            int slot = wb >> 4, rem = wb & 15;
            int wb2 = (((slot ^ (row & 7)) << 4) | rem);
            *(u32*)(Wl + ((row << 6) + (wb2 >> 1))) = v;
        }
    }
    if (tid < 64) {
        int j = tid;
        cb[0][j] = bcomb[j];
        cb[1][j] = ldv(b_ih, j, isf)       + ldv(b_hh, j, isf);
        cb[2][j] = ldv(b_ih, 64 + j, isf)  + ldv(b_hh, 64 + j, isf);
        cb[3][j] = ldv(b_ih, 128 + j, isf);
        cb[4][j] = ldv(b_hh, 128 + j, isf);
        cb[5][j] = ldv(W_out, (long)j * 64 + 0, isf);
        cb[6][j] = ldv(W_out, (long)j * 64 + 1, isf);
        cb[7][j] = ldv(W_out, (long)j * 64 + 2, isf);
        if (j < 3) cbo[j] = ldv(b_out, j, isf);
    }
    __syncthreads();
    int w = tid >> 6, lane = tid & 63;
    int cl = lane & 15, q = lane >> 4;
    u16* hAw = &hA[w][0][0];
    int t0 = q >> 1;

    int wt = blockIdx.x * 4 + w;
    const int WSTRIDE = gridDim.x * 4;

    u32x4 aw; s16x8 hpA, hpB;
    if (wt < NT) {
        long nb = (long)wt * 16;
        aw  = *(const u32x4*)(aggb + ((long)t0 * NN + nb + cl) * 8 + (q & 1) * 4);
        hpA = ld8bf(h_prev, (nb + cl) * 64 + q * 8, isf);
        hpB = ld8bf(h_prev, (nb + cl) * 64 + 32 + q * 8, isf);
    }
    while (wt < NT) {
        int cwt = wt;
        u32x4 caw = aw; s16x8 chp0 = hpA, chp1 = hpB;
        wt += WSTRIDE;
        if (wt < NT) {
            long nb = (long)wt * 16;
            aw  = *(const u32x4*)(aggb + ((long)t0 * NN + nb + cl) * 8 + (q & 1) * 4);
            hpA = ld8bf(h_prev, (nb + cl) * 64 + q * 8, isf);
            hpB = ld8bf(h_prev, (nb + cl) * 64 + 32 + q * 8, isf);
        }
        long nb = (long)cwt * 16;
        {
            FragU fa;
            fa.q[0] = ((ull)caw[1] << 32) | caw[0];
            fa.q[1] = ((ull)caw[3] << 32) | caw[2];
            #pragma unroll
            for (int c = 0; c < 4; c++) {
                f32x4 hacc = (f32x4){0.f, 0.f, 0.f, 0.f};
                s16x8 bfr = *(const s16x8*)(Wcb + (c * 16 + cl) * 32 + q * 8);
                hacc = __builtin_amdgcn_mfma_f32_16x16x32_bf16(fa.v, bfr, hacc, 0, 0, 0);
                float bc = cb[0][c * 16 + cl];
                #pragma unroll
                for (int reg = 0; reg < 4; reg++) {
                    float hv = fmaxf(hacc[reg] + bc, 0.f);
                    hAw[(q * 4 + reg) * 72 + c * 16 + cl] = f2bf(hv);
                }
            }
        }
        asm volatile("" ::: "memory");
        const u16* hrow = hAw + cl * 72;
        FragU ha0, ha1;
        #pragma unroll
        for (int j = 0; j < 8; j++) {
            ha0.u[j] = hrow[q * 8 + j];
            ha1.u[j] = hrow[32 + q * 8 + j];
        }

        float p0[4] = {0,0,0,0}, p1[4] = {0,0,0,0}, p2[4] = {0,0,0,0};
        #pragma unroll
        for (int ch = 0; ch < 2; ch++) {
            f32x4 accr[2], accz[2], accin[2], acchn[2];
            #pragma unroll
            for (int cc = 0; cc < 2; cc++) {
                int j = (ch * 2 + cc) * 16 + cl;
                float br_ = cb[1][j], bz_ = cb[2][j], bi_ = cb[3][j], bh_ = cb[4][j];
                accr[cc]  = (f32x4){br_, br_, br_, br_};
                accz[cc]  = (f32x4){bz_, bz_, bz_, bz_};
                accin[cc] = (f32x4){bi_, bi_, bi_, bi_};
                acchn[cc] = (f32x4){bh_, bh_, bh_, bh_};
            }
            #pragma unroll
            for (int s = 0; s < 2; s++) {
                s16x8 hf  = s ? ha1.v : ha0.v;
                s16x8 hpf = s ? chp1 : chp0;
                int sl8 = ((s * 4 + q) ^ (cl & 7)) * 8;
                #pragma unroll
                for (int cc = 0; cc < 2; cc++) {
                    int rr = (ch * 2 + cc) * 16 + cl;
                    const u16* pw = Wl + rr * 64 + sl8;
                    s16x8 bir  = *(const s16x8*)(pw);
                    s16x8 biz  = *(const s16x8*)(pw + 4096);
                    s16x8 bin2 = *(const s16x8*)(pw + 8192);
                    s16x8 bhr  = *(const s16x8*)(pw + 12288);
                    s16x8 bhz  = *(const s16x8*)(pw + 16384);
                    s16x8 bhn2 = *(const s16x8*)(pw + 20480);
                    accr[cc]  = __builtin_amdgcn_mfma_f32_16x16x32_bf16(hf,  bir,  accr[cc], 0, 0, 0);
                    accr[cc]  = __builtin_amdgcn_mfma_f32_16x16x32_bf16(hpf, bhr,  accr[cc], 0, 0, 0);
                    accz[cc]  = __builtin_amdgcn_mfma_f32_16x16x32_bf16(hf,  biz,  accz[cc], 0, 0, 0);
                    accz[cc]  = __builtin_amdgcn_mfma_f32_16x16x32_bf16(hpf, bhz,  accz[cc], 0, 0, 0);
                    accin[cc] = __builtin_amdgcn_mfma_f32_16x16x32_bf16(hf,  bin2, accin[cc], 0, 0, 0);
                    acchn[cc] = __builtin_amdgcn_mfma_f32_16x16x32_bf16(hpf, bhn2, acchn[cc], 0, 0, 0);
                }
            }
            #pragma unroll
            for (int cc = 0; cc < 2; cc++) {
                int j = (ch * 2 + cc) * 16 + cl;
                float wo0 = cb[5][j], wo1 = cb[6][j], wo2 = cb[7][j];
                #pragma unroll
                for (int reg = 0; reg < 4; reg++) {
                    float rr = sigm(accr[cc][reg]);
                    float zz = sigm(accz[cc][reg]);
                    float ng = tanhf_(accin[cc][reg] + rr * acchn[cc][reg]);
                    long n = nb + q * 4 + reg;
                    float hp = ldv(h_prev, n * 64 + j, isf);
                    float hx = (1.f - zz) * ng + zz * hp;
                    stv(out, n * 64 + j, hx, isf);
                    p0[reg] += hx * wo0;
                    p1[reg] += hx * wo1;
                    p2[reg] += hx * wo2;
                }
            }
        }
        #pragma unroll
        for (int reg = 0; reg < 4; reg++) {
            #pragma unroll
            for (int off2 = 1; off2 < 16; off2 <<= 1) {
                p0[reg] += __shfl_xor(p0[reg], off2);
                p1[reg] += __shfl_xor(p1[reg], off2);
                p2[reg] += __shfl_xor(p2[reg], off2);
            }
        }
        if (cl == 0) {
            #pragma unroll
            for (int reg = 0; reg < 4; reg++) {
                long n = nb + q * 4 + reg;
                long pb = (long)NN * 64 + n * 3;
                stv(out, pb + 0, p0[reg] + cbo[0], isf);
                stv(out, pb + 1, p1[reg] + cbo[1], isf);
                stv(out, pb + 2, p2[reg] + cbo[2], isf);
            }
        }
    }
}

extern "C" void kernel_launch(void* const* d_in, const int* in_sizes, int n_in,
                              void* d_out, int out_size, void* d_ws, size_t ws_size,
                              hipStream_t stream) {
    const void* x      = d_in[0];
    const void* h_prev = d_in[1];
    const int* en      = (const int*)d_in[2];
    const int* eh      = (const int*)d_in[3];
    const int* ea      = (const int*)d_in[4];
    const void* W_conv = d_in[5];
    const void* b_conv = d_in[6];
    const void* W_mix  = d_in[7];
    const void* b_mix  = d_in[8];
    const void* W_ih   = d_in[9];
    const void* W_hh   = d_in[10];
    const void* b_ih   = d_in[11];
    const void* b_hh   = d_in[12];
    const void* W_out  = d_in[13];
    const void* b_out  = d_in[14];
    void* out          = d_out;

    float* ws    = (float*)d_ws;
    u32* bkt1    = (u32*)(ws + OFF_BKT1);
    u32* bkt2    = (u32*)(ws + OFF_BKT2);
    u32* exb     = (u32*)(ws + OFF_EXB);
    int* fscan   = (int*)(ws + OFF_FSC);
    u32* aggb    = (u32*)(ws + OFF_BKT1);   // alias: bkt1 dead after hopA
    float* bcomb = ws + OFF_BCOMB;
    u16* Wihb    = (u16*)(ws + OFF_WIHB);
    u16* Whhb    = (u16*)(ws + OFF_WHHB);
    u16* Wcb     = (u16*)(ws + OFF_WCB);
    u32* flag    = (u32*)(ws + OFF_FLAG);
    int* tot     = (int*)(ws + OFF_TOT);

    detect_kernel<<<1, 256, 0, stream>>>((const u32*)x, flag);
    setup_kernel<<<(XBASE + 255) / 256, 256, 0, stream>>>(
        W_conv, b_conv, W_mix, b_mix, W_ih, W_hh,
        bcomb, Wihb, Whhb, Wcb, flag);
    countC<<<NCB2, 1024, 0, stream>>>(en, eh, ea, fscan);
    scanA2<<<SCB2, 256, 0, stream>>>(fscan, tot);
    scanB2<<<1, 1024, 0, stream>>>(tot);
    scanC2<<<SCB2, 256, 0, stream>>>(fscan, tot);
    placeC<0><<<NCB2, 1024, 0, stream>>>(en, eh, ea, fscan, bkt1);
    placeC<1><<<NCB2, 1024, 0, stream>>>(en, eh, ea, fscan, bkt2);
    hopA<<<NB1, 512, 0, stream>>>(fscan, bkt1, x, exb, flag);
    hopB<<<NB2, 256, 0, stream>>>(fscan, bkt2, exb, aggb);
    epilogue<<<512, 256, 0, stream>>>(aggb, bcomb, Wihb, Wcb,
                                      b_ih, b_hh, h_prev, W_out, b_out, out, flag);
}

// Round 13
// 287.437 us; speedup vs baseline: 1.3739x; 1.0140x over previous
//
#include <hip/hip_runtime.h>

#define NN      100000
#define MHE     200000
#define EE      2000000
#define H1      400000      // hedge keys (2 types)
#define K2N     200000      // node keys (2 types)
#define NB1     782         // side-1 coarse buckets (512 hedge-keys each)
#define NB2     782         // side-2 coarse buckets (256 node-keys each)
#define NCB2    320         // partition blocks
#define CHK2    6250        // edges per partition block (320*6250 = EE exactly)
#define FCN     500480      // (NB1+NB2)*NCB2 flat counters
#define SCB2    489         // ceil(FCN/1024)
#define CAP1    3584        // max items per side-1 bucket (mean 2560)
#define CAP2    3584        // max items per side-2 bucket (mean 2560)
#define NT      6250        // epilogue warp-tiles (NN/16)

typedef unsigned short u16;
typedef unsigned int   u32;
typedef unsigned long long ull;
typedef __attribute__((ext_vector_type(8))) short  s16x8;
typedef __attribute__((ext_vector_type(4))) float  f32x4;
typedef __attribute__((ext_vector_type(4))) unsigned int u32x4;

__device__ __forceinline__ float bf2f(u16 u) { return __uint_as_float(((u32)u) << 16); }
__device__ __forceinline__ u16 f2bf(float f) {
    u32 u = __float_as_uint(f);
    return (u16)((u + 0x7fffu + ((u >> 16) & 1u)) >> 16);
}
__device__ __forceinline__ float ldv(const void* p, long i, int isf32) {
    return isf32 ? ((const float*)p)[i] : bf2f(((const u16*)p)[i]);
}
__device__ __forceinline__ u16 ldb(const void* p, long i, int isf32) {
    return isf32 ? f2bf(((const float*)p)[i]) : ((const u16*)p)[i];
}
__device__ __forceinline__ void stv(void* p, long i, float v, int isf32) {
    if (isf32) ((float*)p)[i] = v;
    else       ((u16*)p)[i] = f2bf(v);
}

union FragU { s16x8 v; ull q[2]; u16 u[8]; };

__device__ __forceinline__ s16x8 ld8bf(const void* p, long off, int isf32) {
    FragU f;
    if (isf32) {
        const float* fp = (const float*)p + off;
        f32x4 a = *(const f32x4*)fp;
        f32x4 b = *(const f32x4*)(fp + 4);
        f.u[0]=f2bf(a[0]); f.u[1]=f2bf(a[1]); f.u[2]=f2bf(a[2]); f.u[3]=f2bf(a[3]);
        f.u[4]=f2bf(b[0]); f.u[5]=f2bf(b[1]); f.u[6]=f2bf(b[2]); f.u[7]=f2bf(b[3]);
    } else {
        u32x4 w = *(const u32x4*)((const u16*)p + off);
        f.q[0] = ((ull)w[1] << 32) | w[0];
        f.q[1] = ((ull)w[3] << 32) | w[2];
    }
    return f.v;
}

// fast transcendentals: v_rcp_f32 approx (~2 ulp) -- error << bf16 rounding
__device__ __forceinline__ float frcp_(float x) { return __builtin_amdgcn_rcpf(x); }
__device__ __forceinline__ float sigm(float x)  { return frcp_(1.f + __expf(-x)); }
__device__ __forceinline__ float tanhf_(float x){ return 1.f - 2.f * frcp_(1.f + __expf(2.f * x)); }

// ---- ws layout (4-byte units) ----
// ws_size is ~268MB (fillBuffer evidence, round 12); layout kept <= 7,714,347 f.
#define OFF_BKT1  0            // u32[2,000,000]; aggb u32[1,600,000] aliases
#define OFF_BKT2  2000000      // u32[2,000,000]
#define OFF_EXB   4000000      // u32[3,200,000] -> ends 7,200,000
#define OFF_FSC   7200000      // int[FCN+1]     -> ends 7,700,481 (scan + sentinel)
#define OFF_TOT   7700481      // int[SCB2=489]  -> ends 7,700,970
#define OFF_BCOMB 7700970      // f32[64]
#define OFF_WIHB  7701034      // u16[12288] (6144 f)
#define OFF_WHHB  7707178      // u16[12288]
#define OFF_WCB   7713322      // u16[2048] (1024 f)
#define OFF_FLAG  7714346      // u32 -> ends 7,714,347

__global__ void detect_kernel(const u32* __restrict__ xw, u32* __restrict__ flag) {
    __shared__ int cnt;
    if (threadIdx.x == 0) cnt = 0;
    __syncthreads();
    int hits = 0;
    for (int i = threadIdx.x; i < 1024; i += 256) {
        float v = bf2f((u16)(xw[i] & 0xffffu));
        if (!(fabsf(v) < 1e10f)) hits++;
    }
    atomicAdd(&cnt, hits);
    __syncthreads();
    if (threadIdx.x == 0) flag[0] = (cnt >= 16) ? 1u : 0u;
}

#define XBASE 26688
__global__ __launch_bounds__(256) void setup_kernel(
        const void* __restrict__ W_conv, const void* __restrict__ b_conv,
        const void* __restrict__ W_mix,  const void* __restrict__ b_mix,
        const void* __restrict__ W_ih,   const void* __restrict__ W_hh,
        float* __restrict__ bcomb, u16* __restrict__ Wihb, u16* __restrict__ Whhb,
        u16* __restrict__ Wcb, const u32* __restrict__ flag) {
    int isf = (int)flag[0];
    int gid = blockIdx.x * 256 + threadIdx.x;
    if (gid < 12288) {
        Wihb[gid] = ldb(W_ih, gid, isf);
    } else if (gid < 24576) {
        int i = gid - 12288;
        Whhb[i] = ldb(W_hh, i, isf);
    } else if (gid < 26624) {
        int i = gid - 24576;
        int j = i >> 5, k = i & 31;
        int t0 = k >> 4, kk = k & 15;
        float acc = 0.f;
        for (int c = 0; c < 64; c++)
            acc += ldv(W_conv, (t0 * 16 + kk) * 64 + c, isf) * ldv(W_mix, (t0 * 64 + c) * 64 + j, isf);
        Wcb[i] = f2bf(acc);
    } else if (gid < XBASE) {
        int j = gid - 26624;
        if (j < 64) {
            float acc = ldv(b_mix, j, isf);
            for (int c = 0; c < 128; c++)
                acc += ldv(b_conv, c, isf) * ldv(W_mix, c * 64 + j, isf);
            bcomb[j] = acc;
        }
    }
}

// per-block coarse histograms, both sides fused. fcnt layout: [bucket][block]
// side-1 buckets 512-keys wide (>>9), side-2 buckets 256-keys wide (>>8).
__global__ __launch_bounds__(1024) void countC(const int* __restrict__ en, const int* __restrict__ eh,
                                               const int* __restrict__ ea, int* __restrict__ fcnt) {
    __shared__ int c[NB1 + NB2];
    int g = blockIdx.x, tid = threadIdx.x;
    for (int i = tid; i < NB1 + NB2; i += 1024) c[i] = 0;
    __syncthreads();
    int s = g * CHK2;
    for (int i = s + tid; i < s + CHK2; i += 1024) {
        int t = ea[i];
        atomicAdd(&c[(t * MHE + eh[i]) >> 9], 1);
        atomicAdd(&c[NB1 + ((t * NN + en[i]) >> 8)], 1);
    }
    __syncthreads();
    for (int b = tid; b < NB1 + NB2; b += 1024) fcnt[b * NCB2 + g] = c[b];
}

// hierarchical exclusive scan of fcnt[FCN] in place
__global__ __launch_bounds__(256) void scanA2(int* __restrict__ a, int* __restrict__ tot) {
    __shared__ int lds[256];
    int g = blockIdx.x, t = threadIdx.x;
    int base = g * 1024 + t * 4;
    int v[4]; int s = 0;
    #pragma unroll
    for (int j = 0; j < 4; j++) { v[j] = (base + j < FCN) ? a[base + j] : 0; s += v[j]; }
    lds[t] = s;
    __syncthreads();
    for (int d = 1; d < 256; d <<= 1) {
        int tmp = (t >= d) ? lds[t - d] : 0;
        __syncthreads();
        lds[t] += tmp;
        __syncthreads();
    }
    int run = lds[t] - s;
    #pragma unroll
    for (int j = 0; j < 4; j++) { if (base + j < FCN) a[base + j] = run; run += v[j]; }
    if (t == 255) tot[g] = lds[255];
}

__global__ __launch_bounds__(1024) void scanB2(int* __restrict__ tot) {
    __shared__ int lds[1024];
    int t = threadIdx.x;
    int v = (t < SCB2) ? tot[t] : 0;
    lds[t] = v;
    __syncthreads();
    for (int d = 1; d < 1024; d <<= 1) {
        int tmp = (t >= d) ? lds[t - d] : 0;
        __syncthreads();
        lds[t] += tmp;
        __syncthreads();
    }
    if (t < SCB2) tot[t] = lds[t] - v;
}

__global__ __launch_bounds__(256) void scanC2(int* __restrict__ a, const int* __restrict__ tot) {
    int g = blockIdx.x, t = threadIdx.x;
    int add = tot[g];
    int base = g * 1024 + t * 4;
    #pragma unroll
    for (int j = 0; j < 4; j++)
        if (base + j < FCN) a[base + j] += add;
    if (g == 0 && t == 0) a[FCN] = 2 * EE;   // sentinel: end of side-2
}

// FUSED placement: edges read ONCE; full keys cached in LDS; both sides
// direct-scattered with LDS cursors + fscan bases. No staging sort, no scan,
// no binary search. Runs per (bucket,block) ~8 consecutive u32 -> ~2x line amp.
__global__ __launch_bounds__(1024) void placeAB(const int* __restrict__ en, const int* __restrict__ eh,
                                                const int* __restrict__ ea, const int* __restrict__ fscan,
                                                u32* __restrict__ bkt1, u32* __restrict__ bkt2) {
    __shared__ u32 A[CHK2];      // k1 full (25 KB)
    __shared__ u32 Bk[CHK2];     // k2 full (25 KB)
    __shared__ int cnt[NB1];     // cursors (3.1 KB); NB1 == NB2
    __shared__ int base_[NB1];   // fscan bases (3.1 KB)
    int g = blockIdx.x, tid = threadIdx.x;
    int s = g * CHK2;
    for (int i = tid; i < CHK2; i += 1024) {
        int t = ea[s + i];
        A[i]  = (u32)(t * MHE + eh[s + i]);
        Bk[i] = (u32)(t * NN  + en[s + i]);
    }
    for (int b = tid; b < NB1; b += 1024) {
        cnt[b] = 0;
        base_[b] = fscan[b * NCB2 + g];
    }
    __syncthreads();
    // side 1: bkt1[pos] = (k1&511)<<17 | node
    for (int i = tid; i < CHK2; i += 1024) {
        u32 k1 = A[i];
        int b = (int)(k1 >> 9);
        int r = atomicAdd(&cnt[b], 1);
        u32 t = (k1 >= (u32)MHE) ? 1u : 0u;
        u32 nd = Bk[i] - t * (u32)NN;
        bkt1[base_[b] + r] = ((k1 & 511u) << 17) | nd;
    }
    __syncthreads();
    for (int b = tid; b < NB2; b += 1024) {
        cnt[b] = 0;
        base_[b] = fscan[NB1 * NCB2 + b * NCB2 + g] - EE;
    }
    __syncthreads();
    // side 2: bkt2[pos] = (k2&255)<<19 | k1
    for (int i = tid; i < CHK2; i += 1024) {
        u32 k2 = Bk[i];
        int b = (int)(k2 >> 8);
        int r = atomicAdd(&cnt[b], 1);
        bkt2[base_[b] + r] = ((k2 & 255u) << 19) | A[i];
    }
}

// hopA: one block per side-1 coarse bucket; fine CSR in LDS; register gather
// unrolled x4; per-group WORK-STEALING key tickets (tail balance).
__global__ __launch_bounds__(512) void hopA(const int* __restrict__ fscan, const u32* __restrict__ bkt1,
                                            const void* __restrict__ x, u32* __restrict__ exb,
                                            const u32* __restrict__ flag) {
    __shared__ int fcnt[512], foff[513], sbuf[512];
    __shared__ int snod[CAP1];
    __shared__ int tick;
    int isf = (int)flag[0];
    int c = blockIdx.x, tid = threadIdx.x;
    int beg = fscan[c * NCB2], end = fscan[(c + 1) * NCB2];
    fcnt[tid] = 0;
    if (tid == 0) tick = 0;
    __syncthreads();
    for (int i = beg + tid; i < end; i += 512)
        atomicAdd(&fcnt[bkt1[i] >> 17], 1);
    __syncthreads();
    int v = fcnt[tid];
    sbuf[tid] = v;
    __syncthreads();
    for (int d = 1; d < 512; d <<= 1) {
        int tmp = (tid >= d) ? sbuf[tid - d] : 0;
        __syncthreads();
        sbuf[tid] += tmp;
        __syncthreads();
    }
    foff[tid] = sbuf[tid] - v;
    fcnt[tid] = 0;
    if (tid == 511) foff[512] = sbuf[511];
    __syncthreads();
    for (int i = beg + tid; i < end; i += 512) {
        u32 p = bkt1[i];
        int k = (int)(p >> 17);
        int r = atomicAdd(&fcnt[k], 1);
        snod[foff[k] + r] = (int)(p & 0x1FFFFu);
    }
    __syncthreads();
    int lane = tid & 63;
    int sub = lane & 7;
    for (;;) {
        int kk;
        if (sub == 0) kk = atomicAdd(&tick, 1);
        kk = __shfl(kk, lane & 56);
        if (kk >= 512) break;
        int key = c * 512 + kk;
        if (key >= H1) break;
        int fb = foff[kk], fe = foff[kk + 1];
        float a0 = 0.f, a1 = 0.f, b0 = 0.f, b1 = 0.f;
        float c0 = 0.f, c1 = 0.f, d0 = 0.f, d1 = 0.f;
        int j = fb;
        if (isf) {
            const float* xf = (const float*)x;
            for (; j + 3 < fe; j += 4) {
                long n0 = (long)snod[j], n1 = (long)snod[j+1];
                long n2 = (long)snod[j+2], n3 = (long)snod[j+3];
                a0 += xf[n0 * 16 + 2 * sub]; a1 += xf[n0 * 16 + 2 * sub + 1];
                b0 += xf[n1 * 16 + 2 * sub]; b1 += xf[n1 * 16 + 2 * sub + 1];
                c0 += xf[n2 * 16 + 2 * sub]; c1 += xf[n2 * 16 + 2 * sub + 1];
                d0 += xf[n3 * 16 + 2 * sub]; d1 += xf[n3 * 16 + 2 * sub + 1];
            }
            for (; j < fe; j++) {
                long n0 = (long)snod[j];
                a0 += xf[n0 * 16 + 2 * sub];
                a1 += xf[n0 * 16 + 2 * sub + 1];
            }
        } else {
            const u32* xu = (const u32*)x;
            for (; j + 3 < fe; j += 4) {
                u32 w0 = xu[(long)snod[j]   * 8 + sub];
                u32 w1 = xu[(long)snod[j+1] * 8 + sub];
                u32 w2 = xu[(long)snod[j+2] * 8 + sub];
                u32 w3 = xu[(long)snod[j+3] * 8 + sub];
                a0 += bf2f((u16)(w0 & 0xffffu)); a1 += bf2f((u16)(w0 >> 16));
                b0 += bf2f((u16)(w1 & 0xffffu)); b1 += bf2f((u16)(w1 >> 16));
                c0 += bf2f((u16)(w2 & 0xffffu)); c1 += bf2f((u16)(w2 >> 16));
                d0 += bf2f((u16)(w3 & 0xffffu)); d1 += bf2f((u16)(w3 >> 16));
            }
            for (; j < fe; j++) {
                u32 w = xu[(long)snod[j] * 8 + sub];
                a0 += bf2f((u16)(w & 0xffffu));
                a1 += bf2f((u16)(w >> 16));
            }
        }
        float s0 = (a0 + b0) + (c0 + d0);
        float s1 = (a1 + b1) + (c1 + d1);
        int d = fe - fb;
        float inv = d > 0 ? 1.0f / (float)d : 0.f;
        exb[(long)key * 8 + sub] = (u32)f2bf(s0 * inv) | ((u32)f2bf(s1 * inv) << 16);
    }
}

// hopB: one block (256 thr) per 256-key side-2 bucket; fine CSR in LDS,
// gather unrolled x4; work-stealing key tickets.
__global__ __launch_bounds__(256) void hopB(const int* __restrict__ fscan, const u32* __restrict__ bkt2,
                                            const u32* __restrict__ exb, u32* __restrict__ aggb) {
    __shared__ int fcnt[256], foff[257], sbuf[256];
    __shared__ int shed[CAP2];
    __shared__ int tick;
    int c = blockIdx.x, tid = threadIdx.x;
    int beg = fscan[NB1 * NCB2 + c * NCB2] - EE;
    int end = fscan[NB1 * NCB2 + (c + 1) * NCB2] - EE;
    fcnt[tid] = 0;
    if (tid == 0) tick = 0;
    __syncthreads();
    for (int i = beg + tid; i < end; i += 256)
        atomicAdd(&fcnt[bkt2[i] >> 19], 1);
    __syncthreads();
    int v = fcnt[tid];
    sbuf[tid] = v;
    __syncthreads();
    for (int d = 1; d < 256; d <<= 1) {
        int tmp = (tid >= d) ? sbuf[tid - d] : 0;
        __syncthreads();
        sbuf[tid] += tmp;
        __syncthreads();
    }
    foff[tid] = sbuf[tid] - v;
    fcnt[tid] = 0;
    if (tid == 255) foff[256] = sbuf[255];
    __syncthreads();
    for (int i = beg + tid; i < end; i += 256) {
        u32 p = bkt2[i];
        int k = (int)(p >> 19);
        int r = atomicAdd(&fcnt[k], 1);
        shed[foff[k] + r] = (int)(p & 0x7FFFFu);
    }
    __syncthreads();
    int lane = tid & 63;
    int sub = lane & 7;
    for (;;) {
        int kk;
        if (sub == 0) kk = atomicAdd(&tick, 1);
        kk = __shfl(kk, lane & 56);
        if (kk >= 256) break;
        int key = c * 256 + kk;
        if (key >= K2N) break;
        int fb = foff[kk], fe = foff[kk + 1];
        float a0 = 0.f, a1 = 0.f, b0 = 0.f, b1 = 0.f;
        float c0 = 0.f, c1 = 0.f, d0 = 0.f, d1 = 0.f;
        int j = fb;
        for (; j + 3 < fe; j += 4) {
            u32 w0 = exb[(long)shed[j]   * 8 + sub];
            u32 w1 = exb[(long)shed[j+1] * 8 + sub];
            u32 w2 = exb[(long)shed[j+2] * 8 + sub];
            u32 w3 = exb[(long)shed[j+3] * 8 + sub];
            a0 += bf2f((u16)(w0 & 0xffffu)); a1 += bf2f((u16)(w0 >> 16));
            b0 += bf2f((u16)(w1 & 0xffffu)); b1 += bf2f((u16)(w1 >> 16));
            c0 += bf2f((u16)(w2 & 0xffffu)); c1 += bf2f((u16)(w2 >> 16));
            d0 += bf2f((u16)(w3 & 0xffffu)); d1 += bf2f((u16)(w3 >> 16));
        }
        for (; j < fe; j++) {
            u32 w = exb[(long)shed[j] * 8 + sub];
            a0 += bf2f((u16)(w & 0xffffu));
            a1 += bf2f((u16)(w >> 16));
        }
        float s0 = (a0 + b0) + (c0 + d0);
        float s1 = (a1 + b1) + (c1 + d1);
        int d = fe - fb;
        float inv = d > 0 ? 1.0f / (float)d : 0.f;
        aggb[(long)key * 8 + sub] = (u32)f2bf(s0 * inv) | ((u32)f2bf(s1 * inv) << 16);
    }
}

// MFMA epilogue v3 (measured-good): weights in LDS (XOR-swizzled),
// multi-tile warps with depth-1 prefetch, grid 512.
__global__ __launch_bounds__(256) void epilogue(const u32* __restrict__ aggb,
                                                const float* __restrict__ bcomb,
                                                const u16* __restrict__ WihbG,
                                                const u16* __restrict__ Wcb,
                                                const void* __restrict__ b_ih, const void* __restrict__ b_hh,
                                                const void* __restrict__ h_prev,
                                                const void* __restrict__ W_out, const void* __restrict__ b_out,
                                                void* __restrict__ out,
                                                const u32* __restrict__ flag) {
    __shared__ u16 Wl[24576];      // 48KB: rows 0..191 = Wih, 192..383 = Whh (swizzled)
    __shared__ u16 hA[4][16][72];  // 9.2KB
    __shared__ float cb[8][64];    // bc, br, bz, bin, bhn, wo0, wo1, wo2
    __shared__ float cbo[3];
    int isf = (int)flag[0];
    int tid = threadIdx.x;
    {
        const u32* gw = (const u32*)WihbG;   // Wihb||Whhb contiguous in ws
        for (int i = tid; i < 12288; i += 256) {
            u32 v = gw[i];
            int row = i >> 5;
            int wb = (i & 31) * 4;
            int slot = wb >> 4, rem = wb & 15;
            int wb2 = (((slot ^ (row & 7)) << 4) | rem);
            *(u32*)(Wl + ((row << 6) + (wb2 >> 1))) = v;
        }
    }
    if (tid < 64) {
        int j = tid;
        cb[0][j] = bcomb[j];
        cb[1][j] = ldv(b_ih, j, isf)       + ldv(b_hh, j, isf);
        cb[2][j] = ldv(b_ih, 64 + j, isf)  + ldv(b_hh, 64 + j, isf);
        cb[3][j] = ldv(b_ih, 128 + j, isf);
        cb[4][j] = ldv(b_hh, 128 + j, isf);
        cb[5][j] = ldv(W_out, (long)j * 64 + 0, isf);
        cb[6][j] = ldv(W_out, (long)j * 64 + 1, isf);
        cb[7][j] = ldv(W_out, (long)j * 64 + 2, isf);
        if (j < 3) cbo[j] = ldv(b_out, j, isf);
    }
    __syncthreads();
    int w = tid >> 6, lane = tid & 63;
    int cl = lane & 15, q = lane >> 4;
    u16* hAw = &hA[w][0][0];
    int t0 = q >> 1;

    int wt = blockIdx.x * 4 + w;
    const int WSTRIDE = gridDim.x * 4;

    u32x4 aw; s16x8 hpA, hpB;
    if (wt < NT) {
        long nb = (long)wt * 16;
        aw  = *(const u32x4*)(aggb + ((long)t0 * NN + nb + cl) * 8 + (q & 1) * 4);
        hpA = ld8bf(h_prev, (nb + cl) * 64 + q * 8, isf);
        hpB = ld8bf(h_prev, (nb + cl) * 64 + 32 + q * 8, isf);
    }
    while (wt < NT) {
        int cwt = wt;
        u32x4 caw = aw; s16x8 chp0 = hpA, chp1 = hpB;
        wt += WSTRIDE;
        if (wt < NT) {
            long nb = (long)wt * 16;
            aw  = *(const u32x4*)(aggb + ((long)t0 * NN + nb + cl) * 8 + (q & 1) * 4);
            hpA = ld8bf(h_prev, (nb + cl) * 64 + q * 8, isf);
            hpB = ld8bf(h_prev, (nb + cl) * 64 + 32 + q * 8, isf);
        }
        long nb = (long)cwt * 16;
        {
            FragU fa;
            fa.q[0] = ((ull)caw[1] << 32) | caw[0];
            fa.q[1] = ((ull)caw[3] << 32) | caw[2];
            #pragma unroll
            for (int c = 0; c < 4; c++) {
                f32x4 hacc = (f32x4){0.f, 0.f, 0.f, 0.f};
                s16x8 bfr = *(const s16x8*)(Wcb + (c * 16 + cl) * 32 + q * 8);
                hacc = __builtin_amdgcn_mfma_f32_16x16x32_bf16(fa.v, bfr, hacc, 0, 0, 0);
                float bc = cb[0][c * 16 + cl];
                #pragma unroll
                for (int reg = 0; reg < 4; reg++) {
                    float hv = fmaxf(hacc[reg] + bc, 0.f);
                    hAw[(q * 4 + reg) * 72 + c * 16 + cl] = f2bf(hv);
                }
            }
        }
        asm volatile("" ::: "memory");
        const u16* hrow = hAw + cl * 72;
        FragU ha0, ha1;
        #pragma unroll
        for (int j = 0; j < 8; j++) {
            ha0.u[j] = hrow[q * 8 + j];
            ha1.u[j] = hrow[32 + q * 8 + j];
        }

        float p0[4] = {0,0,0,0}, p1[4] = {0,0,0,0}, p2[4] = {0,0,0,0};
        #pragma unroll
        for (int ch = 0; ch < 2; ch++) {
            f32x4 accr[2], accz[2], accin[2], acchn[2];
            #pragma unroll
            for (int cc = 0; cc < 2; cc++) {
                int j = (ch * 2 + cc) * 16 + cl;
                float br_ = cb[1][j], bz_ = cb[2][j], bi_ = cb[3][j], bh_ = cb[4][j];
                accr[cc]  = (f32x4){br_, br_, br_, br_};
                accz[cc]  = (f32x4){bz_, bz_, bz_, bz_};
                accin[cc] = (f32x4){bi_, bi_, bi_, bi_};
                acchn[cc] = (f32x4){bh_, bh_, bh_, bh_};
            }
            #pragma unroll
            for (int s = 0; s < 2; s++) {
                s16x8 hf  = s ? ha1.v : ha0.v;
                s16x8 hpf = s ? chp1 : chp0;
                int sl8 = ((s * 4 + q) ^ (cl & 7)) * 8;
                #pragma unroll
                for (int cc = 0; cc < 2; cc++) {
                    int rr = (ch * 2 + cc) * 16 + cl;
                    const u16* pw = Wl + rr * 64 + sl8;
                    s16x8 bir  = *(const s16x8*)(pw);
                    s16x8 biz  = *(const s16x8*)(pw + 4096);
                    s16x8 bin2 = *(const s16x8*)(pw + 8192);
                    s16x8 bhr  = *(const s16x8*)(pw + 12288);
                    s16x8 bhz  = *(const s16x8*)(pw + 16384);
                    s16x8 bhn2 = *(const s16x8*)(pw + 20480);
                    accr[cc]  = __builtin_amdgcn_mfma_f32_16x16x32_bf16(hf,  bir,  accr[cc], 0, 0, 0);
                    accr[cc]  = __builtin_amdgcn_mfma_f32_16x16x32_bf16(hpf, bhr,  accr[cc], 0, 0, 0);
                    accz[cc]  = __builtin_amdgcn_mfma_f32_16x16x32_bf16(hf,  biz,  accz[cc], 0, 0, 0);
                    accz[cc]  = __builtin_amdgcn_mfma_f32_16x16x32_bf16(hpf, bhz,  accz[cc], 0, 0, 0);
                    accin[cc] = __builtin_amdgcn_mfma_f32_16x16x32_bf16(hf,  bin2, accin[cc], 0, 0, 0);
                    acchn[cc] = __builtin_amdgcn_mfma_f32_16x16x32_bf16(hpf, bhn2, acchn[cc], 0, 0, 0);
                }
            }
            #pragma unroll
            for (int cc = 0; cc < 2; cc++) {
                int j = (ch * 2 + cc) * 16 + cl;
                float wo0 = cb[5][j], wo1 = cb[6][j], wo2 = cb[7][j];
                #pragma unroll
                for (int reg = 0; reg < 4; reg++) {
                    float rr = sigm(accr[cc][reg]);
                    float zz = sigm(accz[cc][reg]);
                    float ng = tanhf_(accin[cc][reg] + rr * acchn[cc][reg]);
                    long n = nb + q * 4 + reg;
                    float hp = ldv(h_prev, n * 64 + j, isf);
                    float hx = (1.f - zz) * ng + zz * hp;
                    stv(out, n * 64 + j, hx, isf);
                    p0[reg] += hx * wo0;
                    p1[reg] += hx * wo1;
                    p2[reg] += hx * wo2;
                }
            }
        }
        #pragma unroll
        for (int reg = 0; reg < 4; reg++) {
            #pragma unroll
            for (int off2 = 1; off2 < 16; off2 <<= 1) {
                p0[reg] += __shfl_xor(p0[reg], off2);
                p1[reg] += __shfl_xor(p1[reg], off2);
                p2[reg] += __shfl_xor(p2[reg], off2);
            }
        }
        if (cl == 0) {
            #pragma unroll
            for (int reg = 0; reg < 4; reg++) {
                long n = nb + q * 4 + reg;
                long pb = (long)NN * 64 + n * 3;
                stv(out, pb + 0, p0[reg] + cbo[0], isf);
                stv(out, pb + 1, p1[reg] + cbo[1], isf);
                stv(out, pb + 2, p2[reg] + cbo[2], isf);
            }
        }
    }
}

extern "C" void kernel_launch(void* const* d_in, const int* in_sizes, int n_in,
                              void* d_out, int out_size, void* d_ws, size_t ws_size,
                              hipStream_t stream) {
    const void* x      = d_in[0];
    const void* h_prev = d_in[1];
    const int* en      = (const int*)d_in[2];
    const int* eh      = (const int*)d_in[3];
    const int* ea      = (const int*)d_in[4];
    const void* W_conv = d_in[5];
    const void* b_conv = d_in[6];
    const void* W_mix  = d_in[7];
    const void* b_mix  = d_in[8];
    const void* W_ih   = d_in[9];
    const void* W_hh   = d_in[10];
    const void* b_ih   = d_in[11];
    const void* b_hh   = d_in[12];
    const void* W_out  = d_in[13];
    const void* b_out  = d_in[14];
    void* out          = d_out;

    float* ws    = (float*)d_ws;
    u32* bkt1    = (u32*)(ws + OFF_BKT1);
    u32* bkt2    = (u32*)(ws + OFF_BKT2);
    u32* exb     = (u32*)(ws + OFF_EXB);
    int* fscan   = (int*)(ws + OFF_FSC);
    u32* aggb    = (u32*)(ws + OFF_BKT1);   // alias: bkt1 dead after hopA
    float* bcomb = ws + OFF_BCOMB;
    u16* Wihb    = (u16*)(ws + OFF_WIHB);
    u16* Whhb    = (u16*)(ws + OFF_WHHB);
    u16* Wcb     = (u16*)(ws + OFF_WCB);
    u32* flag    = (u32*)(ws + OFF_FLAG);
    int* tot     = (int*)(ws + OFF_TOT);

    detect_kernel<<<1, 256, 0, stream>>>((const u32*)x, flag);
    setup_kernel<<<(XBASE + 255) / 256, 256, 0, stream>>>(
        W_conv, b_conv, W_mix, b_mix, W_ih, W_hh,
        bcomb, Wihb, Whhb, Wcb, flag);
    countC<<<NCB2, 1024, 0, stream>>>(en, eh, ea, fscan);
    scanA2<<<SCB2, 256, 0, stream>>>(fscan, tot);
    scanB2<<<1, 1024, 0, stream>>>(tot);
    scanC2<<<SCB2, 256, 0, stream>>>(fscan, tot);
    placeAB<<<NCB2, 1024, 0, stream>>>(en, eh, ea, fscan, bkt1, bkt2);
    hopA<<<NB1, 512, 0, stream>>>(fscan, bkt1, x, exb, flag);
    hopB<<<NB2, 256, 0, stream>>>(fscan, bkt2, exb, aggb);
    epilogue<<<512, 256, 0, stream>>>(aggb, bcomb, Wihb, Wcb,
                                      b_ih, b_hh, h_prev, W_out, b_out, out, flag);
}

// Round 14
// 286.085 us; speedup vs baseline: 1.3804x; 1.0047x over previous
//
#include <hip/hip_runtime.h>

#define NN      100000
#define MHE     200000
#define EE      2000000
#define H1      400000      // hedge keys (2 types)
#define K2N     200000      // node keys (2 types)
#define NB1     782         // side-1 coarse buckets (512 hedge-keys each)
#define NB2     782         // side-2 coarse buckets (256 node-keys each)
#define NCB2    320         // partition blocks
#define CHK2    6250        // edges per partition block (320*6250 = EE exactly)
#define FCN     500480      // (NB1+NB2)*NCB2 flat counters
#define SCB2    489         // ceil(FCN/1024)
#define CAP1    3584        // max items per side-1 bucket (mean 2560)
#define CAP2    3584        // max items per side-2 bucket (mean 2560)
#define NT      6250        // epilogue warp-tiles (NN/16)

typedef unsigned short u16;
typedef unsigned int   u32;
typedef unsigned long long ull;
typedef __attribute__((ext_vector_type(8))) short  s16x8;
typedef __attribute__((ext_vector_type(4))) float  f32x4;
typedef __attribute__((ext_vector_type(4))) unsigned int u32x4;

__device__ __forceinline__ float bf2f(u16 u) { return __uint_as_float(((u32)u) << 16); }
__device__ __forceinline__ u16 f2bf(float f) {
    u32 u = __float_as_uint(f);
    return (u16)((u + 0x7fffu + ((u >> 16) & 1u)) >> 16);
}
__device__ __forceinline__ float ldv(const void* p, long i, int isf32) {
    return isf32 ? ((const float*)p)[i] : bf2f(((const u16*)p)[i]);
}
__device__ __forceinline__ u16 ldb(const void* p, long i, int isf32) {
    return isf32 ? f2bf(((const float*)p)[i]) : ((const u16*)p)[i];
}
__device__ __forceinline__ void stv(void* p, long i, float v, int isf32) {
    if (isf32) ((float*)p)[i] = v;
    else       ((u16*)p)[i] = f2bf(v);
}

union FragU { s16x8 v; ull q[2]; u16 u[8]; };

__device__ __forceinline__ s16x8 ld8bf(const void* p, long off, int isf32) {
    FragU f;
    if (isf32) {
        const float* fp = (const float*)p + off;
        f32x4 a = *(const f32x4*)fp;
        f32x4 b = *(const f32x4*)(fp + 4);
        f.u[0]=f2bf(a[0]); f.u[1]=f2bf(a[1]); f.u[2]=f2bf(a[2]); f.u[3]=f2bf(a[3]);
        f.u[4]=f2bf(b[0]); f.u[5]=f2bf(b[1]); f.u[6]=f2bf(b[2]); f.u[7]=f2bf(b[3]);
    } else {
        u32x4 w = *(const u32x4*)((const u16*)p + off);
        f.q[0] = ((ull)w[1] << 32) | w[0];
        f.q[1] = ((ull)w[3] << 32) | w[2];
    }
    return f.v;
}

// fast transcendentals: v_rcp_f32 approx (~2 ulp) -- error << bf16 rounding
__device__ __forceinline__ float frcp_(float x) { return __builtin_amdgcn_rcpf(x); }
__device__ __forceinline__ float sigm(float x)  { return frcp_(1.f + __expf(-x)); }
__device__ __forceinline__ float tanhf_(float x){ return 1.f - 2.f * frcp_(1.f + __expf(2.f * x)); }

// ---- ws layout (4-byte units) ----
#define OFF_BKT1  0            // u32[2,000,000]; aggb u32[1,600,000] aliases
#define OFF_BKT2  2000000      // u32[2,000,000]
#define OFF_EXB   4000000      // u32[3,200,000] -> ends 7,200,000
#define OFF_FSC   7200000      // int[FCN+1]     -> ends 7,700,481 (scan + sentinel)
#define OFF_TOT   7700481      // int[SCB2=489]  -> ends 7,700,970
#define OFF_BCOMB 7700970      // f32[64]
#define OFF_WIHB  7701034      // u16[12288] (6144 f)
#define OFF_WHHB  7707178      // u16[12288]
#define OFF_WCB   7713322      // u16[2048] (1024 f)
#define OFF_FLAG  7714346      // u32 -> ends 7,714,347

__global__ void detect_kernel(const u32* __restrict__ xw, u32* __restrict__ flag) {
    __shared__ int cnt;
    if (threadIdx.x == 0) cnt = 0;
    __syncthreads();
    int hits = 0;
    for (int i = threadIdx.x; i < 1024; i += 256) {
        float v = bf2f((u16)(xw[i] & 0xffffu));
        if (!(fabsf(v) < 1e10f)) hits++;
    }
    atomicAdd(&cnt, hits);
    __syncthreads();
    if (threadIdx.x == 0) flag[0] = (cnt >= 16) ? 1u : 0u;
}

#define XBASE 26688
__global__ __launch_bounds__(256) void setup_kernel(
        const void* __restrict__ W_conv, const void* __restrict__ b_conv,
        const void* __restrict__ W_mix,  const void* __restrict__ b_mix,
        const void* __restrict__ W_ih,   const void* __restrict__ W_hh,
        float* __restrict__ bcomb, u16* __restrict__ Wihb, u16* __restrict__ Whhb,
        u16* __restrict__ Wcb, const u32* __restrict__ flag) {
    int isf = (int)flag[0];
    int gid = blockIdx.x * 256 + threadIdx.x;
    if (gid < 12288) {
        Wihb[gid] = ldb(W_ih, gid, isf);
    } else if (gid < 24576) {
        int i = gid - 12288;
        Whhb[i] = ldb(W_hh, i, isf);
    } else if (gid < 26624) {
        int i = gid - 24576;
        int j = i >> 5, k = i & 31;
        int t0 = k >> 4, kk = k & 15;
        float acc = 0.f;
        for (int c = 0; c < 64; c++)
            acc += ldv(W_conv, (t0 * 16 + kk) * 64 + c, isf) * ldv(W_mix, (t0 * 64 + c) * 64 + j, isf);
        Wcb[i] = f2bf(acc);
    } else if (gid < XBASE) {
        int j = gid - 26624;
        if (j < 64) {
            float acc = ldv(b_mix, j, isf);
            for (int c = 0; c < 128; c++)
                acc += ldv(b_conv, c, isf) * ldv(W_mix, c * 64 + j, isf);
            bcomb[j] = acc;
        }
    }
}

// per-block coarse histograms, both sides fused. fcnt layout: [bucket][block]
__global__ __launch_bounds__(1024) void countC(const int* __restrict__ en, const int* __restrict__ eh,
                                               const int* __restrict__ ea, int* __restrict__ fcnt) {
    __shared__ int c[NB1 + NB2];
    int g = blockIdx.x, tid = threadIdx.x;
    for (int i = tid; i < NB1 + NB2; i += 1024) c[i] = 0;
    __syncthreads();
    int s = g * CHK2;
    for (int i = s + tid; i < s + CHK2; i += 1024) {
        int t = ea[i];
        atomicAdd(&c[(t * MHE + eh[i]) >> 9], 1);
        atomicAdd(&c[NB1 + ((t * NN + en[i]) >> 8)], 1);
    }
    __syncthreads();
    for (int b = tid; b < NB1 + NB2; b += 1024) fcnt[b * NCB2 + g] = c[b];
}

// hierarchical exclusive scan of fcnt[FCN] in place
__global__ __launch_bounds__(256) void scanA2(int* __restrict__ a, int* __restrict__ tot) {
    __shared__ int lds[256];
    int g = blockIdx.x, t = threadIdx.x;
    int base = g * 1024 + t * 4;
    int v[4]; int s = 0;
    #pragma unroll
    for (int j = 0; j < 4; j++) { v[j] = (base + j < FCN) ? a[base + j] : 0; s += v[j]; }
    lds[t] = s;
    __syncthreads();
    for (int d = 1; d < 256; d <<= 1) {
        int tmp = (t >= d) ? lds[t - d] : 0;
        __syncthreads();
        lds[t] += tmp;
        __syncthreads();
    }
    int run = lds[t] - s;
    #pragma unroll
    for (int j = 0; j < 4; j++) { if (base + j < FCN) a[base + j] = run; run += v[j]; }
    if (t == 255) tot[g] = lds[255];
}

__global__ __launch_bounds__(1024) void scanB2(int* __restrict__ tot) {
    __shared__ int lds[1024];
    int t = threadIdx.x;
    int v = (t < SCB2) ? tot[t] : 0;
    lds[t] = v;
    __syncthreads();
    for (int d = 1; d < 1024; d <<= 1) {
        int tmp = (t >= d) ? lds[t - d] : 0;
        __syncthreads();
        lds[t] += tmp;
        __syncthreads();
    }
    if (t < SCB2) tot[t] = lds[t] - v;
}

__global__ __launch_bounds__(256) void scanC2(int* __restrict__ a, const int* __restrict__ tot) {
    int g = blockIdx.x, t = threadIdx.x;
    int add = tot[g];
    int base = g * 1024 + t * 4;
    #pragma unroll
    for (int j = 0; j < 4; j++)
        if (base + j < FCN) a[base + j] += add;
    if (g == 0 && t == 0) a[FCN] = 2 * EE;   // sentinel: end of side-2
}

// FUSED placement: edges read ONCE; full keys cached in LDS; both sides
// direct-scattered with LDS cursors + fscan bases.
__global__ __launch_bounds__(1024) void placeAB(const int* __restrict__ en, const int* __restrict__ eh,
                                                const int* __restrict__ ea, const int* __restrict__ fscan,
                                                u32* __restrict__ bkt1, u32* __restrict__ bkt2) {
    __shared__ u32 A[CHK2];      // k1 full (25 KB)
    __shared__ u32 Bk[CHK2];     // k2 full (25 KB)
    __shared__ int cnt[NB1];     // cursors; NB1 == NB2
    __shared__ int base_[NB1];   // fscan bases
    int g = blockIdx.x, tid = threadIdx.x;
    int s = g * CHK2;
    for (int i = tid; i < CHK2; i += 1024) {
        int t = ea[s + i];
        A[i]  = (u32)(t * MHE + eh[s + i]);
        Bk[i] = (u32)(t * NN  + en[s + i]);
    }
    for (int b = tid; b < NB1; b += 1024) {
        cnt[b] = 0;
        base_[b] = fscan[b * NCB2 + g];
    }
    __syncthreads();
    // side 1: bkt1[pos] = (k1&511)<<17 | node
    for (int i = tid; i < CHK2; i += 1024) {
        u32 k1 = A[i];
        int b = (int)(k1 >> 9);
        int r = atomicAdd(&cnt[b], 1);
        u32 t = (k1 >= (u32)MHE) ? 1u : 0u;
        u32 nd = Bk[i] - t * (u32)NN;
        bkt1[base_[b] + r] = ((k1 & 511u) << 17) | nd;
    }
    __syncthreads();
    for (int b = tid; b < NB2; b += 1024) {
        cnt[b] = 0;
        base_[b] = fscan[NB1 * NCB2 + b * NCB2 + g] - EE;
    }
    __syncthreads();
    // side 2: bkt2[pos] = (k2&255)<<19 | k1
    for (int i = tid; i < CHK2; i += 1024) {
        u32 k2 = Bk[i];
        int b = (int)(k2 >> 8);
        int r = atomicAdd(&cnt[b], 1);
        bkt2[base_[b] + r] = ((k2 & 255u) << 19) | A[i];
    }
}

// hopA: one block per side-1 coarse bucket; fine CSR in LDS; register gather
// unrolled x4; per-group work-stealing key tickets.
__global__ __launch_bounds__(512) void hopA(const int* __restrict__ fscan, const u32* __restrict__ bkt1,
                                            const void* __restrict__ x, u32* __restrict__ exb,
                                            const u32* __restrict__ flag) {
    __shared__ int fcnt[512], foff[513], sbuf[512];
    __shared__ int snod[CAP1];
    __shared__ int tick;
    int isf = (int)flag[0];
    int c = blockIdx.x, tid = threadIdx.x;
    int beg = fscan[c * NCB2], end = fscan[(c + 1) * NCB2];
    fcnt[tid] = 0;
    if (tid == 0) tick = 0;
    __syncthreads();
    for (int i = beg + tid; i < end; i += 512)
        atomicAdd(&fcnt[bkt1[i] >> 17], 1);
    __syncthreads();
    int v = fcnt[tid];
    sbuf[tid] = v;
    __syncthreads();
    for (int d = 1; d < 512; d <<= 1) {
        int tmp = (tid >= d) ? sbuf[tid - d] : 0;
        __syncthreads();
        sbuf[tid] += tmp;
        __syncthreads();
    }
    foff[tid] = sbuf[tid] - v;
    fcnt[tid] = 0;
    if (tid == 511) foff[512] = sbuf[511];
    __syncthreads();
    for (int i = beg + tid; i < end; i += 512) {
        u32 p = bkt1[i];
        int k = (int)(p >> 17);
        int r = atomicAdd(&fcnt[k], 1);
        snod[foff[k] + r] = (int)(p & 0x1FFFFu);
    }
    __syncthreads();
    int lane = tid & 63;
    int sub = lane & 7;
    for (;;) {
        int kk;
        if (sub == 0) kk = atomicAdd(&tick, 1);
        kk = __shfl(kk, lane & 56);
        if (kk >= 512) break;
        int key = c * 512 + kk;
        if (key >= H1) break;
        int fb = foff[kk], fe = foff[kk + 1];
        float a0 = 0.f, a1 = 0.f, b0 = 0.f, b1 = 0.f;
        float c0 = 0.f, c1 = 0.f, d0 = 0.f, d1 = 0.f;
        int j = fb;
        if (isf) {
            const float* xf = (const float*)x;
            for (; j + 3 < fe; j += 4) {
                long n0 = (long)snod[j], n1 = (long)snod[j+1];
                long n2 = (long)snod[j+2], n3 = (long)snod[j+3];
                a0 += xf[n0 * 16 + 2 * sub]; a1 += xf[n0 * 16 + 2 * sub + 1];
                b0 += xf[n1 * 16 + 2 * sub]; b1 += xf[n1 * 16 + 2 * sub + 1];
                c0 += xf[n2 * 16 + 2 * sub]; c1 += xf[n2 * 16 + 2 * sub + 1];
                d0 += xf[n3 * 16 + 2 * sub]; d1 += xf[n3 * 16 + 2 * sub + 1];
            }
            for (; j < fe; j++) {
                long n0 = (long)snod[j];
                a0 += xf[n0 * 16 + 2 * sub];
                a1 += xf[n0 * 16 + 2 * sub + 1];
            }
        } else {
            const u32* xu = (const u32*)x;
            for (; j + 3 < fe; j += 4) {
                u32 w0 = xu[(long)snod[j]   * 8 + sub];
                u32 w1 = xu[(long)snod[j+1] * 8 + sub];
                u32 w2 = xu[(long)snod[j+2] * 8 + sub];
                u32 w3 = xu[(long)snod[j+3] * 8 + sub];
                a0 += bf2f((u16)(w0 & 0xffffu)); a1 += bf2f((u16)(w0 >> 16));
                b0 += bf2f((u16)(w1 & 0xffffu)); b1 += bf2f((u16)(w1 >> 16));
                c0 += bf2f((u16)(w2 & 0xffffu)); c1 += bf2f((u16)(w2 >> 16));
                d0 += bf2f((u16)(w3 & 0xffffu)); d1 += bf2f((u16)(w3 >> 16));
            }
            for (; j < fe; j++) {
                u32 w = xu[(long)snod[j] * 8 + sub];
                a0 += bf2f((u16)(w & 0xffffu));
                a1 += bf2f((u16)(w >> 16));
            }
        }
        float s0 = (a0 + b0) + (c0 + d0);
        float s1 = (a1 + b1) + (c1 + d1);
        int d = fe - fb;
        float inv = d > 0 ? 1.0f / (float)d : 0.f;
        exb[(long)key * 8 + sub] = (u32)f2bf(s0 * inv) | ((u32)f2bf(s1 * inv) << 16);
    }
}

// hopB: one block (256 thr) per 256-key side-2 bucket; fine CSR in LDS,
// gather unrolled x4; work-stealing key tickets.
__global__ __launch_bounds__(256) void hopB(const int* __restrict__ fscan, const u32* __restrict__ bkt2,
                                            const u32* __restrict__ exb, u32* __restrict__ aggb) {
    __shared__ int fcnt[256], foff[257], sbuf[256];
    __shared__ int shed[CAP2];
    __shared__ int tick;
    int c = blockIdx.x, tid = threadIdx.x;
    int beg = fscan[NB1 * NCB2 + c * NCB2] - EE;
    int end = fscan[NB1 * NCB2 + (c + 1) * NCB2] - EE;
    fcnt[tid] = 0;
    if (tid == 0) tick = 0;
    __syncthreads();
    for (int i = beg + tid; i < end; i += 256)
        atomicAdd(&fcnt[bkt2[i] >> 19], 1);
    __syncthreads();
    int v = fcnt[tid];
    sbuf[tid] = v;
    __syncthreads();
    for (int d = 1; d < 256; d <<= 1) {
        int tmp = (tid >= d) ? sbuf[tid - d] : 0;
        __syncthreads();
        sbuf[tid] += tmp;
        __syncthreads();
    }
    foff[tid] = sbuf[tid] - v;
    fcnt[tid] = 0;
    if (tid == 255) foff[256] = sbuf[255];
    __syncthreads();
    for (int i = beg + tid; i < end; i += 256) {
        u32 p = bkt2[i];
        int k = (int)(p >> 19);
        int r = atomicAdd(&fcnt[k], 1);
        shed[foff[k] + r] = (int)(p & 0x7FFFFu);
    }
    __syncthreads();
    int lane = tid & 63;
    int sub = lane & 7;
    for (;;) {
        int kk;
        if (sub == 0) kk = atomicAdd(&tick, 1);
        kk = __shfl(kk, lane & 56);
        if (kk >= 256) break;
        int key = c * 256 + kk;
        if (key >= K2N) break;
        int fb = foff[kk], fe = foff[kk + 1];
        float a0 = 0.f, a1 = 0.f, b0 = 0.f, b1 = 0.f;
        float c0 = 0.f, c1 = 0.f, d0 = 0.f, d1 = 0.f;
        int j = fb;
        for (; j + 3 < fe; j += 4) {
            u32 w0 = exb[(long)shed[j]   * 8 + sub];
            u32 w1 = exb[(long)shed[j+1] * 8 + sub];
            u32 w2 = exb[(long)shed[j+2] * 8 + sub];
            u32 w3 = exb[(long)shed[j+3] * 8 + sub];
            a0 += bf2f((u16)(w0 & 0xffffu)); a1 += bf2f((u16)(w0 >> 16));
            b0 += bf2f((u16)(w1 & 0xffffu)); b1 += bf2f((u16)(w1 >> 16));
            c0 += bf2f((u16)(w2 & 0xffffu)); c1 += bf2f((u16)(w2 >> 16));
            d0 += bf2f((u16)(w3 & 0xffffu)); d1 += bf2f((u16)(w3 >> 16));
        }
        for (; j < fe; j++) {
            u32 w = exb[(long)shed[j] * 8 + sub];
            a0 += bf2f((u16)(w & 0xffffu));
            a1 += bf2f((u16)(w >> 16));
        }
        float s0 = (a0 + b0) + (c0 + d0);
        float s1 = (a1 + b1) + (c1 + d1);
        int d = fe - fb;
        float inv = d > 0 ? 1.0f / (float)d : 0.f;
        aggb[(long)key * 8 + sub] = (u32)f2bf(s0 * inv) | ((u32)f2bf(s1 * inv) << 16);
    }
}

// MFMA epilogue v4: 512-thread blocks (8 warps) share one 48KB weight image ->
// 16 waves/CU at the same 2-blocks/CU LDS budget (round 13 was 8 waves/CU).
// Weights in LDS (XOR-swizzled), multi-tile warps with depth-1 prefetch.
__global__ __launch_bounds__(512) void epilogue(const u32* __restrict__ aggb,
                                                const float* __restrict__ bcomb,
                                                const u16* __restrict__ WihbG,
                                                const u16* __restrict__ Wcb,
                                                const void* __restrict__ b_ih, const void* __restrict__ b_hh,
                                                const void* __restrict__ h_prev,
                                                const void* __restrict__ W_out, const void* __restrict__ b_out,
                                                void* __restrict__ out,
                                                const u32* __restrict__ flag) {
    __shared__ u16 Wl[24576];      // 48KB: rows 0..191 = Wih, 192..383 = Whh (swizzled)
    __shared__ u16 hA[8][16][72];  // 18.4KB (8 warps)
    __shared__ float cb[8][64];    // bc, br, bz, bin, bhn, wo0, wo1, wo2
    __shared__ float cbo[3];
    int isf = (int)flag[0];
    int tid = threadIdx.x;
    {
        const u32* gw = (const u32*)WihbG;   // Wihb||Whhb contiguous in ws
        for (int i = tid; i < 12288; i += 512) {
            u32 v = gw[i];
            int row = i >> 5;
            int wb = (i & 31) * 4;
            int slot = wb >> 4, rem = wb & 15;
            int wb2 = (((slot ^ (row & 7)) << 4) | rem);
            *(u32*)(Wl + ((row << 6) + (wb2 >> 1))) = v;
        }
    }
    if (tid < 64) {
        int j = tid;
        cb[0][j] = bcomb[j];
        cb[1][j] = ldv(b_ih, j, isf)       + ldv(b_hh, j, isf);
        cb[2][j] = ldv(b_ih, 64 + j, isf)  + ldv(b_hh, 64 + j, isf);
        cb[3][j] = ldv(b_ih, 128 + j, isf);
        cb[4][j] = ldv(b_hh, 128 + j, isf);
        cb[5][j] = ldv(W_out, (long)j * 64 + 0, isf);
        cb[6][j] = ldv(W_out, (long)j * 64 + 1, isf);
        cb[7][j] = ldv(W_out, (long)j * 64 + 2, isf);
        if (j < 3) cbo[j] = ldv(b_out, j, isf);
    }
    __syncthreads();
    int w = tid >> 6, lane = tid & 63;
    int cl = lane & 15, q = lane >> 4;
    u16* hAw = &hA[w][0][0];
    int t0 = q >> 1;

    int wt = blockIdx.x * 8 + w;
    const int WSTRIDE = gridDim.x * 8;

    u32x4 aw; s16x8 hpA, hpB;
    if (wt < NT) {
        long nb = (long)wt * 16;
        aw  = *(const u32x4*)(aggb + ((long)t0 * NN + nb + cl) * 8 + (q & 1) * 4);
        hpA = ld8bf(h_prev, (nb + cl) * 64 + q * 8, isf);
        hpB = ld8bf(h_prev, (nb + cl) * 64 + 32 + q * 8, isf);
    }
    while (wt < NT) {
        int cwt = wt;
        u32x4 caw = aw; s16x8 chp0 = hpA, chp1 = hpB;
        wt += WSTRIDE;
        if (wt < NT) {
            long nb = (long)wt * 16;
            aw  = *(const u32x4*)(aggb + ((long)t0 * NN + nb + cl) * 8 + (q & 1) * 4);
            hpA = ld8bf(h_prev, (nb + cl) * 64 + q * 8, isf);
            hpB = ld8bf(h_prev, (nb + cl) * 64 + 32 + q * 8, isf);
        }
        long nb = (long)cwt * 16;
        {
            FragU fa;
            fa.q[0] = ((ull)caw[1] << 32) | caw[0];
            fa.q[1] = ((ull)caw[3] << 32) | caw[2];
            #pragma unroll
            for (int c = 0; c < 4; c++) {
                f32x4 hacc = (f32x4){0.f, 0.f, 0.f, 0.f};
                s16x8 bfr = *(const s16x8*)(Wcb + (c * 16 + cl) * 32 + q * 8);
                hacc = __builtin_amdgcn_mfma_f32_16x16x32_bf16(fa.v, bfr, hacc, 0, 0, 0);
                float bc = cb[0][c * 16 + cl];
                #pragma unroll
                for (int reg = 0; reg < 4; reg++) {
                    float hv = fmaxf(hacc[reg] + bc, 0.f);
                    hAw[(q * 4 + reg) * 72 + c * 16 + cl] = f2bf(hv);
                }
            }
        }
        asm volatile("" ::: "memory");
        const u16* hrow = hAw + cl * 72;
        FragU ha0, ha1;
        #pragma unroll
        for (int j = 0; j < 8; j++) {
            ha0.u[j] = hrow[q * 8 + j];
            ha1.u[j] = hrow[32 + q * 8 + j];
        }

        float p0[4] = {0,0,0,0}, p1[4] = {0,0,0,0}, p2[4] = {0,0,0,0};
        #pragma unroll
        for (int ch = 0; ch < 2; ch++) {
            f32x4 accr[2], accz[2], accin[2], acchn[2];
            #pragma unroll
            for (int cc = 0; cc < 2; cc++) {
                int j = (ch * 2 + cc) * 16 + cl;
                float br_ = cb[1][j], bz_ = cb[2][j], bi_ = cb[3][j], bh_ = cb[4][j];
                accr[cc]  = (f32x4){br_, br_, br_, br_};
                accz[cc]  = (f32x4){bz_, bz_, bz_, bz_};
                accin[cc] = (f32x4){bi_, bi_, bi_, bi_};
                acchn[cc] = (f32x4){bh_, bh_, bh_, bh_};
            }
            #pragma unroll
            for (int s = 0; s < 2; s++) {
                s16x8 hf  = s ? ha1.v : ha0.v;
                s16x8 hpf = s ? chp1 : chp0;
                int sl8 = ((s * 4 + q) ^ (cl & 7)) * 8;
                #pragma unroll
                for (int cc = 0; cc < 2; cc++) {
                    int rr = (ch * 2 + cc) * 16 + cl;
                    const u16* pw = Wl + rr * 64 + sl8;
                    s16x8 bir  = *(const s16x8*)(pw);
                    s16x8 biz  = *(const s16x8*)(pw + 4096);
                    s16x8 bin2 = *(const s16x8*)(pw + 8192);
                    s16x8 bhr  = *(const s16x8*)(pw + 12288);
                    s16x8 bhz  = *(const s16x8*)(pw + 16384);
                    s16x8 bhn2 = *(const s16x8*)(pw + 20480);
                    accr[cc]  = __builtin_amdgcn_mfma_f32_16x16x32_bf16(hf,  bir,  accr[cc], 0, 0, 0);
                    accr[cc]  = __builtin_amdgcn_mfma_f32_16x16x32_bf16(hpf, bhr,  accr[cc], 0, 0, 0);
                    accz[cc]  = __builtin_amdgcn_mfma_f32_16x16x32_bf16(hf,  biz,  accz[cc], 0, 0, 0);
                    accz[cc]  = __builtin_amdgcn_mfma_f32_16x16x32_bf16(hpf, bhz,  accz[cc], 0, 0, 0);
                    accin[cc] = __builtin_amdgcn_mfma_f32_16x16x32_bf16(hf,  bin2, accin[cc], 0, 0, 0);
                    acchn[cc] = __builtin_amdgcn_mfma_f32_16x16x32_bf16(hpf, bhn2, acchn[cc], 0, 0, 0);
                }
            }
            #pragma unroll
            for (int cc = 0; cc < 2; cc++) {
                int j = (ch * 2 + cc) * 16 + cl;
                float wo0 = cb[5][j], wo1 = cb[6][j], wo2 = cb[7][j];
                #pragma unroll
                for (int reg = 0; reg < 4; reg++) {
                    float rr = sigm(accr[cc][reg]);
                    float zz = sigm(accz[cc][reg]);
                    float ng = tanhf_(accin[cc][reg] + rr * acchn[cc][reg]);
                    long n = nb + q * 4 + reg;
                    float hp = ldv(h_prev, n * 64 + j, isf);
                    float hx = (1.f - zz) * ng + zz * hp;
                    stv(out, n * 64 + j, hx, isf);
                    p0[reg] += hx * wo0;
                    p1[reg] += hx * wo1;
                    p2[reg] += hx * wo2;
                }
            }
        }
        #pragma unroll
        for (int reg = 0; reg < 4; reg++) {
            #pragma unroll
            for (int off2 = 1; off2 < 16; off2 <<= 1) {
                p0[reg] += __shfl_xor(p0[reg], off2);
                p1[reg] += __shfl_xor(p1[reg], off2);
                p2[reg] += __shfl_xor(p2[reg], off2);
            }
        }
        if (cl == 0) {
            #pragma unroll
            for (int reg = 0; reg < 4; reg++) {
                long n = nb + q * 4 + reg;
                long pb = (long)NN * 64 + n * 3;
                stv(out, pb + 0, p0[reg] + cbo[0], isf);
                stv(out, pb + 1, p1[reg] + cbo[1], isf);
                stv(out, pb + 2, p2[reg] + cbo[2], isf);
            }
        }
    }
}

extern "C" void kernel_launch(void* const* d_in, const int* in_sizes, int n_in,
                              void* d_out, int out_size, void* d_ws, size_t ws_size,
                              hipStream_t stream) {
    const void* x      = d_in[0];
    const void* h_prev = d_in[1];
    const int* en      = (const int*)d_in[2];
    const int* eh      = (const int*)d_in[3];
    const int* ea      = (const int*)d_in[4];
    const void* W_conv = d_in[5];
    const void* b_conv = d_in[6];
    const void* W_mix  = d_in[7];
    const void* b_mix  = d_in[8];
    const void* W_ih   = d_in[9];
    const void* W_hh   = d_in[10];
    const void* b_ih   = d_in[11];
    const void* b_hh   = d_in[12];
    const void* W_out  = d_in[13];
    const void* b_out  = d_in[14];
    void* out          = d_out;

    float* ws    = (float*)d_ws;
    u32* bkt1    = (u32*)(ws + OFF_BKT1);
    u32* bkt2    = (u32*)(ws + OFF_BKT2);
    u32* exb     = (u32*)(ws + OFF_EXB);
    int* fscan   = (int*)(ws + OFF_FSC);
    u32* aggb    = (u32*)(ws + OFF_BKT1);   // alias: bkt1 dead after hopA
    float* bcomb = ws + OFF_BCOMB;
    u16* Wihb    = (u16*)(ws + OFF_WIHB);
    u16* Whhb    = (u16*)(ws + OFF_WHHB);
    u16* Wcb     = (u16*)(ws + OFF_WCB);
    u32* flag    = (u32*)(ws + OFF_FLAG);
    int* tot     = (int*)(ws + OFF_TOT);

    detect_kernel<<<1, 256, 0, stream>>>((const u32*)x, flag);
    setup_kernel<<<(XBASE + 255) / 256, 256, 0, stream>>>(
        W_conv, b_conv, W_mix, b_mix, W_ih, W_hh,
        bcomb, Wihb, Whhb, Wcb, flag);
    countC<<<NCB2, 1024, 0, stream>>>(en, eh, ea, fscan);
    scanA2<<<SCB2, 256, 0, stream>>>(fscan, tot);
    scanB2<<<1, 1024, 0, stream>>>(tot);
    scanC2<<<SCB2, 256, 0, stream>>>(fscan, tot);
    placeAB<<<NCB2, 1024, 0, stream>>>(en, eh, ea, fscan, bkt1, bkt2);
    hopA<<<NB1, 512, 0, stream>>>(fscan, bkt1, x, exb, flag);
    hopB<<<NB2, 256, 0, stream>>>(fscan, bkt2, exb, aggb);
    epilogue<<<256, 512, 0, stream>>>(aggb, bcomb, Wihb, Wcb,
                                      b_ih, b_hh, h_prev, W_out, b_out, out, flag);
}